// Round 3
// baseline (1790.224 us; speedup 1.0000x reference)
//
#include <hip/hip_runtime.h>
#include <hip/hip_bf16.h>
#include <math.h>

// Problem constants
constexpr int Bn = 4, Tn = 1024, Cn = 1024, Hn = 16;
constexpr int BT = Bn * Tn;                 // 4096
constexpr long long BTC = (long long)BT * Cn;  // 4M elements
constexpr int CL = 64;                      // chunk length
constexpr int NC = Tn / CL;                 // 16 chunks

typedef __bf16 bf16x8_t __attribute__((ext_vector_type(8)));
typedef float f32x4_t __attribute__((ext_vector_type(4)));
typedef unsigned short us8_t __attribute__((ext_vector_type(8)));

// ---------------------------------------------------------------------------
// mix input for the token-mix LoRA: out = x + (x_prev - x)*x_maa[c]
// ---------------------------------------------------------------------------
__global__ __launch_bounds__(256) void prep_mixin(const float* __restrict__ x,
                                                  const float* __restrict__ x_maa,
                                                  float* __restrict__ out) {
    long long idx = (long long)blockIdx.x * 256 + threadIdx.x;
    if (idx >= BTC) return;
    int c  = (int)(idx & (Cn - 1));
    long long bt = idx >> 10;
    int t  = (int)(bt & (Tn - 1));
    float xv = x[idx];
    float xp = (t > 0) ? x[idx - Cn] : 0.f;
    out[idx] = xv + (xp - xv) * x_maa[c];
}

// ---------------------------------------------------------------------------
// Transpose + convert: W [R][Cc] f32 -> Wt [Cc][R] bf16
// ---------------------------------------------------------------------------
__global__ __launch_bounds__(256) void transp_bf16(const float* __restrict__ W,
                                                   __hip_bfloat16* __restrict__ Wt,
                                                   int R, int Cc) {
    __shared__ float tile[32][33];
    int c0 = blockIdx.x * 32, r0 = blockIdx.y * 32;
    int tx = threadIdx.x & 31, ty = threadIdx.x >> 5;
    #pragma unroll
    for (int i = 0; i < 4; i++)
        tile[ty + 8 * i][tx] = W[(size_t)(r0 + ty + 8 * i) * Cc + c0 + tx];
    __syncthreads();
    #pragma unroll
    for (int i = 0; i < 4; i++)
        Wt[(size_t)(c0 + ty + 8 * i) * R + r0 + tx] = __float2bfloat16(tile[tx][ty + 8 * i]);
}

// ---------------------------------------------------------------------------
// f32 tiled GEMM (small/odd shapes): C = A[M,K]@B[K,N].
// EPI: 1 tanh, 3 logdecay (-exp(extra[col]+acc))
// ---------------------------------------------------------------------------
template <int EPI>
__global__ __launch_bounds__(256) void gemm_f32(const float* __restrict__ A,
                                                const float* __restrict__ Bm,
                                                float* __restrict__ C,
                                                int M, int N, int K,
                                                const float* __restrict__ extra) {
    __shared__ float As[16][64];
    __shared__ float Bs[16][64];
    int tid = threadIdx.x;
    int m0 = blockIdx.y * 64, n0 = blockIdx.x * 64;
    int tx = tid & 15, ty = tid >> 4;
    int ar = tid >> 2, ac = (tid & 3) * 4;
    int br = tid >> 4, bc = (tid & 15) * 4;
    float acc[4][4] = {};

    for (int k0 = 0; k0 < K; k0 += 16) {
        const float* ap = A + (size_t)(m0 + ar) * K + k0 + ac;
        float4 av = *reinterpret_cast<const float4*>(ap);
        As[ac + 0][ar] = av.x; As[ac + 1][ar] = av.y;
        As[ac + 2][ar] = av.z; As[ac + 3][ar] = av.w;
        float4 bv;
        if (n0 + bc + 3 < N) {
            bv = *reinterpret_cast<const float4*>(Bm + (size_t)(k0 + br) * N + n0 + bc);
        } else {
            float tmp[4];
            #pragma unroll
            for (int i = 0; i < 4; i++) {
                int col = n0 + bc + i;
                tmp[i] = (col < N) ? Bm[(size_t)(k0 + br) * N + col] : 0.f;
            }
            bv = make_float4(tmp[0], tmp[1], tmp[2], tmp[3]);
        }
        *reinterpret_cast<float4*>(&Bs[br][bc]) = bv;
        __syncthreads();
        #pragma unroll
        for (int kk = 0; kk < 16; kk++) {
            float4 a4 = *reinterpret_cast<const float4*>(&As[kk][ty * 4]);
            float4 b4 = *reinterpret_cast<const float4*>(&Bs[kk][tx * 4]);
            float aa[4] = {a4.x, a4.y, a4.z, a4.w};
            float bb[4] = {b4.x, b4.y, b4.z, b4.w};
            #pragma unroll
            for (int i = 0; i < 4; i++)
                #pragma unroll
                for (int j = 0; j < 4; j++)
                    acc[i][j] = fmaf(aa[i], bb[j], acc[i][j]);
        }
        __syncthreads();
    }

    #pragma unroll
    for (int i = 0; i < 4; i++) {
        int row = m0 + ty * 4 + i;
        #pragma unroll
        for (int j = 0; j < 4; j++) {
            int col = n0 + tx * 4 + j;
            if (col < N) {
                float v = acc[i][j];
                if (EPI == 1) v = tanhf(v);
                else if (EPI == 3) v = -expf(extra[col] + v);
                C[(size_t)row * N + col] = v;
            }
        }
    }
}

// ---------------------------------------------------------------------------
// bf16 MFMA GEMM: C[M,N] = A[M,K] @ Bt[N,K]^T.  BM=64, BN=128, BK=64.
// 4 waves (2x2), wave tile 32x64, 16x16x32 MFMA, XOR-swizzled LDS.
// EPI: 0 none, 2 silu.  OBF16: write bf16 output.
// ---------------------------------------------------------------------------
template <int EPI, bool OBF16>
__global__ __launch_bounds__(256) void gemm_mfma(const __hip_bfloat16* __restrict__ A,
                                                 const __hip_bfloat16* __restrict__ Bt,
                                                 void* __restrict__ Cout,
                                                 int M, int N, int K) {
    __shared__ alignas(16) unsigned short As[64 * 64];
    __shared__ alignas(16) unsigned short Bs[128 * 64];
    int tid = threadIdx.x;
    int m0 = blockIdx.y * 64, n0 = blockIdx.x * 128;
    int wave = tid >> 6, lane = tid & 63;
    int wm = (wave & 1) * 32, wn = (wave >> 1) * 64;
    int l15 = lane & 15, l4 = lane >> 4;
    f32x4_t acc[2][4] = {};

    for (int k0 = 0; k0 < K; k0 += 64) {
        #pragma unroll
        for (int p = 0; p < 2; p++) {
            int cch = tid + p * 256;            // 0..511
            int row = cch >> 3, slot = cch & 7;
            int s2 = slot ^ (row & 7);
            *reinterpret_cast<us8_t*>(&As[row * 64 + s2 * 8]) =
                *reinterpret_cast<const us8_t*>(&A[(size_t)(m0 + row) * K + k0 + slot * 8]);
        }
        #pragma unroll
        for (int p = 0; p < 4; p++) {
            int cch = tid + p * 256;            // 0..1023
            int row = cch >> 3, slot = cch & 7;
            int s2 = slot ^ (row & 7);
            *reinterpret_cast<us8_t*>(&Bs[row * 64 + s2 * 8]) =
                *reinterpret_cast<const us8_t*>(&Bt[(size_t)(n0 + row) * K + k0 + slot * 8]);
        }
        __syncthreads();
        #pragma unroll
        for (int kw = 0; kw < 2; kw++) {
            int slot = kw * 4 + l4;
            bf16x8_t af[2], bfr[4];
            #pragma unroll
            for (int f = 0; f < 2; f++) {
                int ar = wm + f * 16 + l15;
                af[f] = *reinterpret_cast<const bf16x8_t*>(&As[ar * 64 + (slot ^ (ar & 7)) * 8]);
            }
            #pragma unroll
            for (int f = 0; f < 4; f++) {
                int br = wn + f * 16 + l15;
                bfr[f] = *reinterpret_cast<const bf16x8_t*>(&Bs[br * 64 + (slot ^ (br & 7)) * 8]);
            }
            #pragma unroll
            for (int i = 0; i < 2; i++)
                #pragma unroll
                for (int j = 0; j < 4; j++)
                    acc[i][j] = __builtin_amdgcn_mfma_f32_16x16x32_bf16(af[i], bfr[j], acc[i][j], 0, 0, 0);
        }
        __syncthreads();
    }

    #pragma unroll
    for (int i = 0; i < 2; i++) {
        int rbase = m0 + wm + i * 16 + l4 * 4;
        #pragma unroll
        for (int j = 0; j < 4; j++) {
            int col = n0 + wn + j * 16 + l15;
            #pragma unroll
            for (int q = 0; q < 4; q++) {
                float v = acc[i][j][q];
                if (EPI == 2) v = v / (1.f + expf(-v));
                size_t o = (size_t)(rbase + q) * N + col;
                if (OBF16) ((__hip_bfloat16*)Cout)[o] = __float2bfloat16(v);
                else       ((float*)Cout)[o] = v;
            }
        }
    }
}

// ---------------------------------------------------------------------------
// 5 mix deltas fused with wx/kx/vx/rx/gx build. Block = 8 bt-rows x 256 cols.
// w2 loads amortized 8x; mix staged in LDS (broadcast reads).
// ---------------------------------------------------------------------------
__global__ __launch_bounds__(256) void deltas_mix(const float* __restrict__ x,
                                                  const float* __restrict__ mix160,
                                                  const float* __restrict__ w2,
                                                  const float* __restrict__ wmaa,
                                                  const float* __restrict__ kmaa,
                                                  const float* __restrict__ vmaa,
                                                  const float* __restrict__ rmaa,
                                                  const float* __restrict__ gmaa,
                                                  float* __restrict__ wx,
                                                  __hip_bfloat16* __restrict__ kxb,
                                                  __hip_bfloat16* __restrict__ vxb,
                                                  __hip_bfloat16* __restrict__ rxb,
                                                  __hip_bfloat16* __restrict__ gxb) {
    int tid = threadIdx.x;
    int c = blockIdx.x * 256 + tid;
    int r0 = blockIdx.y * 8;
    __shared__ float m[8][160];
    for (int i = tid; i < 1280; i += 256)
        m[i / 160][i % 160] = mix160[(size_t)(r0 + i / 160) * 160 + (i % 160)];
    __syncthreads();
    float acc[5][8];
    #pragma unroll
    for (int f = 0; f < 5; f++)
        #pragma unroll
        for (int r = 0; r < 8; r++) acc[f][r] = 0.f;
    #pragma unroll
    for (int f = 0; f < 5; f++) {
        for (int dd = 0; dd < 32; dd++) {
            float wv = w2[(size_t)(f * 32 + dd) * Cn + c];
            #pragma unroll
            for (int r = 0; r < 8; r++)
                acc[f][r] = fmaf(m[r][f * 32 + dd], wv, acc[f][r]);
        }
    }
    float wm_ = wmaa[c], km_ = kmaa[c], vm_ = vmaa[c], rm_ = rmaa[c], gm_ = gmaa[c];
    #pragma unroll
    for (int r = 0; r < 8; r++) {
        int row = r0 + r;
        int t = row & (Tn - 1);
        size_t idx = (size_t)row * Cn + c;
        float xv = x[idx];
        float xp = (t > 0) ? x[idx - Cn] : 0.f;
        float sx = xp - xv;
        wx[idx]  = xv + sx * (wm_ + acc[0][r]);
        kxb[idx] = __float2bfloat16(xv + sx * (km_ + acc[1][r]));
        vxb[idx] = __float2bfloat16(xv + sx * (vm_ + acc[2][r]));
        rxb[idx] = __float2bfloat16(xv + sx * (rm_ + acc[3][r]));
        gxb[idx] = __float2bfloat16(xv + sx * (gm_ + acc[4][r]));
    }
}

// ---------------------------------------------------------------------------
// Chunked WKV stage A: per (b,h,chunk):
//   Wtot[ch] = exp(sum lw); Bc[k][v] = sum_tau exp(Lend-Linc[tau])*k*v
// ---------------------------------------------------------------------------
__global__ __launch_bounds__(256) void chunk_summary(const float* __restrict__ kb,
                                                     const float* __restrict__ vb,
                                                     const float* __restrict__ lw,
                                                     float* __restrict__ Bc,
                                                     float* __restrict__ Wtot) {
    int bid = blockIdx.x;
    int c = bid & 15, h = (bid >> 4) & 15, b = bid >> 8;
    size_t gbase = ((size_t)(b * Tn + c * CL) * Hn + h) * 64;
    int tid = threadIdx.x;
    __shared__ float linc[64][68];
    __shared__ float kd[64][68];
    __shared__ float vs[64][68];
    __shared__ float wtp[4][64];
    int wave = tid >> 6, lane = tid & 63;
    {
        float acc = 0.f;
        #pragma unroll
        for (int i = 0; i < 16; i++) {
            int t = wave * 16 + i;
            acc += lw[gbase + (size_t)t * 1024 + lane];
            linc[t][lane] = acc;
        }
        wtp[wave][lane] = acc;
    }
    __syncthreads();
    {
        float off = 0.f;
        for (int g = 0; g < wave; g++) off += wtp[g][lane];
        #pragma unroll
        for (int i = 0; i < 16; i++) linc[wave * 16 + i][lane] += off;
    }
    __syncthreads();
    int t4 = tid >> 2, c0 = (tid & 3) * 16;
    #pragma unroll
    for (int i = 0; i < 4; i++) {
        int ch = c0 + i * 4;
        size_t ga = gbase + (size_t)t4 * 1024 + ch;
        float4 k4 = *reinterpret_cast<const float4*>(kb + ga);
        float4 v4 = *reinterpret_cast<const float4*>(vb + ga);
        float kk[4] = {k4.x, k4.y, k4.z, k4.w};
        float vv[4] = {v4.x, v4.y, v4.z, v4.w};
        #pragma unroll
        for (int j = 0; j < 4; j++) {
            float li = linc[t4][ch + j];
            float lend = linc[63][ch + j];
            kd[t4][ch + j] = kk[j] * expf(lend - li);
            vs[t4][ch + j] = vv[j];
        }
    }
    if (tid < 64) Wtot[(size_t)bid * 64 + tid] = expf(linc[63][tid]);
    __syncthreads();
    int kk = tid >> 2, v0 = (tid & 3) * 16;
    float4 o[4] = {};
    for (int tau = 0; tau < 64; tau++) {
        float kdv = kd[tau][kk];
        #pragma unroll
        for (int j = 0; j < 4; j++) {
            float4 v4 = *reinterpret_cast<const float4*>(&vs[tau][v0 + 4 * j]);
            o[j].x = fmaf(kdv, v4.x, o[j].x);
            o[j].y = fmaf(kdv, v4.y, o[j].y);
            o[j].z = fmaf(kdv, v4.z, o[j].z);
            o[j].w = fmaf(kdv, v4.w, o[j].w);
        }
    }
    #pragma unroll
    for (int j = 0; j < 4; j++)
        *reinterpret_cast<float4*>(Bc + (size_t)bid * 4096 + kk * 64 + v0 + 4 * j) = o[j];
}

// ---------------------------------------------------------------------------
// Stage B: sequential scan over NC=16 chunk states (entry states out).
// ---------------------------------------------------------------------------
__global__ __launch_bounds__(256) void chunk_scan(const float* __restrict__ Bc,
                                                  const float* __restrict__ Wtot,
                                                  float* __restrict__ Sbuf) {
    int bid = blockIdx.x;
    int bh = bid >> 2, vg = bid & 3;
    int kk = threadIdx.x >> 2;
    int v = vg * 16 + (threadIdx.x & 3) * 4;
    float4 S = make_float4(0.f, 0.f, 0.f, 0.f);
    for (int c = 0; c < NC; c++) {
        size_t cb = (size_t)(bh * NC + c) * 4096 + (size_t)kk * 64 + v;
        *reinterpret_cast<float4*>(Sbuf + cb) = S;
        float wt = Wtot[(size_t)(bh * NC + c) * 64 + kk];
        float4 b4 = *reinterpret_cast<const float4*>(Bc + cb);
        S.x = fmaf(wt, S.x, b4.x);
        S.y = fmaf(wt, S.y, b4.y);
        S.z = fmaf(wt, S.z, b4.z);
        S.w = fmaf(wt, S.w, b4.w);
    }
}

// ---------------------------------------------------------------------------
// Stage C: per (b,h,chunk) outputs (recomputes Linc prefix in LDS):
//   Y = mask(Q'K'^T + diag(r.u.k)) @ V + Q' @ S_entry
// ---------------------------------------------------------------------------
__global__ __launch_bounds__(256) void chunk_out(const float* __restrict__ rb,
                                                 const float* __restrict__ kb,
                                                 const float* __restrict__ vb,
                                                 const float* __restrict__ lw,
                                                 const float* __restrict__ Sbuf,
                                                 const float* __restrict__ tf,
                                                 float* __restrict__ y) {
    int bid = blockIdx.x;
    int c = bid & 15, h = (bid >> 4) & 15, b = bid >> 8;
    size_t gbase = ((size_t)(b * Tn + c * CL) * Hn + h) * 64;
    int tid = threadIdx.x;
    __shared__ float qs[64][68], ks[64][68], vs[64][68], as_[64][68], sc[64][68];
    __shared__ float wtp[4][64];
    __shared__ float diag[64];
    int wave = tid >> 6, lane = tid & 63;
    // prefix sums of lw -> as_ (used as linc scratch)
    {
        float acc = 0.f;
        #pragma unroll
        for (int i = 0; i < 16; i++) {
            int t = wave * 16 + i;
            acc += lw[gbase + (size_t)t * 1024 + lane];
            as_[t][lane] = acc;
        }
        wtp[wave][lane] = acc;
    }
    __syncthreads();
    {
        float off = 0.f;
        for (int g = 0; g < wave; g++) off += wtp[g][lane];
        #pragma unroll
        for (int i = 0; i < 16; i++) as_[wave * 16 + i][lane] += off;
    }
    __syncthreads();
    int t = tid >> 2, c0 = (tid & 3) * 16;
    float dpart = 0.f;
    #pragma unroll
    for (int i = 0; i < 4; i++) {
        int ch = c0 + i * 4;
        size_t ga = gbase + (size_t)t * 1024 + ch;
        float4 r4 = *reinterpret_cast<const float4*>(rb + ga);
        float4 k4 = *reinterpret_cast<const float4*>(kb + ga);
        float4 v4 = *reinterpret_cast<const float4*>(vb + ga);
        float4 l4 = *reinterpret_cast<const float4*>(lw + ga);
        float4 li4 = *reinterpret_cast<const float4*>(&as_[t][ch]);
        float4 u4 = *reinterpret_cast<const float4*>(tf + h * 64 + ch);
        float rr[4] = {r4.x, r4.y, r4.z, r4.w};
        float kkv[4] = {k4.x, k4.y, k4.z, k4.w};
        float vv[4] = {v4.x, v4.y, v4.z, v4.w};
        float lwv[4] = {l4.x, l4.y, l4.z, l4.w};
        float li[4] = {li4.x, li4.y, li4.z, li4.w};
        float uu[4] = {u4.x, u4.y, u4.z, u4.w};
        #pragma unroll
        for (int j = 0; j < 4; j++) {
            qs[t][ch + j] = rr[j] * expf(li[j] - lwv[j]);  // exp(Lexc)
            ks[t][ch + j] = kkv[j] * expf(-li[j]);
            vs[t][ch + j] = vv[j];
            dpart = fmaf(rr[j] * uu[j], kkv[j], dpart);
        }
        float4 s4 = *reinterpret_cast<const float4*>(Sbuf + (size_t)bid * 4096 + t * 64 + ch);
        *reinterpret_cast<float4*>(&sc[t][ch]) = s4;
    }
    dpart += __shfl_xor(dpart, 1);
    dpart += __shfl_xor(dpart, 2);
    if ((tid & 3) == 0) diag[t] = dpart;
    __syncthreads();
    {
        int tj = tid & 3;
        float acc[16];
        #pragma unroll
        for (int i = 0; i < 16; i++) acc[i] = 0.f;
        for (int ch = 0; ch < 64; ch += 4) {
            float4 q4 = *reinterpret_cast<const float4*>(&qs[t][ch]);
            #pragma unroll
            for (int i = 0; i < 16; i++) {
                int tau = tj + 4 * i;
                if (tau < t) {
                    float4 k4 = *reinterpret_cast<const float4*>(&ks[tau][ch]);
                    acc[i] += q4.x * k4.x + q4.y * k4.y + q4.z * k4.z + q4.w * k4.w;
                }
            }
        }
        #pragma unroll
        for (int i = 0; i < 16; i++) {
            int tau = tj + 4 * i;
            as_[t][tau] = (tau < t) ? acc[i] : (tau == t ? diag[t] : 0.f);
        }
    }
    __syncthreads();
    int v0 = (tid & 3) * 16;
    float4 o[4] = {};
    for (int tau = 0; tau <= t; tau++) {
        float av = as_[t][tau];
        #pragma unroll
        for (int j = 0; j < 4; j++) {
            float4 v4 = *reinterpret_cast<const float4*>(&vs[tau][v0 + 4 * j]);
            o[j].x = fmaf(av, v4.x, o[j].x);
            o[j].y = fmaf(av, v4.y, o[j].y);
            o[j].z = fmaf(av, v4.z, o[j].z);
            o[j].w = fmaf(av, v4.w, o[j].w);
        }
    }
    for (int k = 0; k < 64; k++) {
        float qv = qs[t][k];
        #pragma unroll
        for (int j = 0; j < 4; j++) {
            float4 s4 = *reinterpret_cast<const float4*>(&sc[k][v0 + 4 * j]);
            o[j].x = fmaf(qv, s4.x, o[j].x);
            o[j].y = fmaf(qv, s4.y, o[j].y);
            o[j].z = fmaf(qv, s4.z, o[j].z);
            o[j].w = fmaf(qv, s4.w, o[j].w);
        }
    }
    #pragma unroll
    for (int j = 0; j < 4; j++)
        *reinterpret_cast<float4*>(y + gbase + (size_t)t * 1024 + v0 + 4 * j) = o[j];
}

// ---------------------------------------------------------------------------
// GroupNorm per (bt,h) over 64 channels (after /8), *ln_w + ln_b, then *g.
// Output bf16 (feeds Wo MFMA GEMM).
// ---------------------------------------------------------------------------
__global__ __launch_bounds__(256) void gn_mul(const float* __restrict__ y,
                                              const __hip_bfloat16* __restrict__ g,
                                              const float* __restrict__ lnw,
                                              const float* __restrict__ lnb,
                                              __hip_bfloat16* __restrict__ fin) {
    int tid = threadIdx.x;
    int lane = tid & 63;
    int wv = tid >> 6;
    int grp = blockIdx.x * 4 + wv;    // bt*16 + h
    int h = grp & 15;
    size_t idx = (size_t)grp * 64 + lane;
    float val = y[idx] * 0.125f;
    float sum = val, sq = val * val;
    #pragma unroll
    for (int off = 32; off > 0; off >>= 1) {
        sum += __shfl_xor(sum, off, 64);
        sq  += __shfl_xor(sq,  off, 64);
    }
    float mu = sum * (1.f / 64.f);
    float var = sq * (1.f / 64.f) - mu * mu;
    float rs = rsqrtf(var + 1e-5f);
    float o = (val - mu) * rs * lnw[h * 64 + lane] + lnb[h * 64 + lane];
    fin[idx] = __float2bfloat16(o * __bfloat162float(g[idx]));
}

// ---------------------------------------------------------------------------
extern "C" void kernel_launch(void* const* d_in, const int* in_sizes, int n_in,
                              void* d_out, int out_size, void* d_ws, size_t ws_size,
                              hipStream_t stream) {
    (void)in_sizes; (void)n_in; (void)out_size; (void)ws_size;
    const float* x      = (const float*)d_in[0];
    const float* x_maa  = (const float*)d_in[1];
    const float* w_maa  = (const float*)d_in[2];
    const float* k_maa  = (const float*)d_in[3];
    const float* v_maa  = (const float*)d_in[4];
    const float* r_maa  = (const float*)d_in[5];
    const float* g_maa  = (const float*)d_in[6];
    const float* tm_w1  = (const float*)d_in[7];
    const float* tm_w2  = (const float*)d_in[8];
    const float* td_w1  = (const float*)d_in[9];
    const float* td_w2  = (const float*)d_in[10];
    const float* t_dec  = (const float*)d_in[11];
    const float* t_first= (const float*)d_in[12];
    const float* Wr     = (const float*)d_in[13];
    const float* Wk     = (const float*)d_in[14];
    const float* Wv     = (const float*)d_in[15];
    const float* Wg     = (const float*)d_in[16];
    const float* Wo     = (const float*)d_in[17];
    const float* ln_w   = (const float*)d_in[18];
    const float* ln_b   = (const float*)d_in[19];
    float* out = (float*)d_out;

    // Byte allocator, 256B aligned
    char* ws = (char*)d_ws;
    size_t off = 0;
    auto alloc = [&](size_t bytes) -> void* {
        void* p = ws + off;
        off = (off + bytes + 255) & ~(size_t)255;
        return p;
    };
    float* mixin  = (float*)alloc(BTC * 4);            // alias: rb
    float* mix160 = (float*)alloc((size_t)BT * 160 * 4);
    float* wxr    = (float*)alloc(BTC * 4);            // wx -> BcB -> ybuf
    __hip_bfloat16* kxb = (__hip_bfloat16*)alloc(BTC * 2);  // alias: fin
    __hip_bfloat16* vxb = (__hip_bfloat16*)alloc(BTC * 2);
    __hip_bfloat16* rxb = (__hip_bfloat16*)alloc(BTC * 2);  // rxb+gxb -> SbB (16MB)
    __hip_bfloat16* gxb = (__hip_bfloat16*)alloc(BTC * 2);
    float* kb  = (float*)alloc(BTC * 4);
    float* vb  = (float*)alloc(BTC * 4);
    __hip_bfloat16* gb = (__hip_bfloat16*)alloc(BTC * 2);
    float* wl1 = (float*)alloc((size_t)BT * 64 * 4);   // alias: WtB
    float* lwb = (float*)alloc(BTC * 4);
    __hip_bfloat16* WrT = (__hip_bfloat16*)alloc((size_t)Cn * Cn * 2);
    __hip_bfloat16* WkT = (__hip_bfloat16*)alloc((size_t)Cn * Cn * 2);
    __hip_bfloat16* WvT = (__hip_bfloat16*)alloc((size_t)Cn * Cn * 2);
    __hip_bfloat16* WgT = (__hip_bfloat16*)alloc((size_t)Cn * Cn * 2);
    __hip_bfloat16* WoT = (__hip_bfloat16*)alloc((size_t)Cn * Cn * 2);
    // Aliases (stream-ordered; producers complete before reuse):
    float* rb   = mixin;           // r projection (mixin dead after LoRA1)
    float* BcB  = wxr;             // chunk contributions (wx dead after wl1 GEMM)
    float* ybuf = wxr;             // recurrence out (BcB dead after chunk_scan)
    float* WtB  = wl1;             // chunk decay totals (wl1 dead after decay GEMM)
    float* SbB  = (float*)rxb;     // entry states, spans rxb+gxb (dead after projections)
    __hip_bfloat16* fin = kxb;     // gn output (kxb dead after k projection)

    dim3 blk(256);
    // weight transpose+convert
    transp_bf16<<<dim3(32, 32), blk, 0, stream>>>(Wr, WrT, Cn, Cn);
    transp_bf16<<<dim3(32, 32), blk, 0, stream>>>(Wk, WkT, Cn, Cn);
    transp_bf16<<<dim3(32, 32), blk, 0, stream>>>(Wv, WvT, Cn, Cn);
    transp_bf16<<<dim3(32, 32), blk, 0, stream>>>(Wg, WgT, Cn, Cn);
    transp_bf16<<<dim3(32, 32), blk, 0, stream>>>(Wo, WoT, Cn, Cn);
    // token-mix LoRA
    prep_mixin<<<dim3((unsigned)((BTC + 255) / 256)), blk, 0, stream>>>(x, x_maa, mixin);
    gemm_f32<1><<<dim3(3, 64), blk, 0, stream>>>(mixin, tm_w1, mix160, BT, 160, Cn, nullptr);
    deltas_mix<<<dim3(4, 512), blk, 0, stream>>>(x, mix160, tm_w2,
                                                 w_maa, k_maa, v_maa, r_maa, g_maa,
                                                 wxr, kxb, vxb, rxb, gxb);
    // projections (bf16 MFMA)
    gemm_mfma<0, false><<<dim3(8, 64), blk, 0, stream>>>(rxb, WrT, rb, BT, Cn, Cn);
    gemm_mfma<0, false><<<dim3(8, 64), blk, 0, stream>>>(kxb, WkT, kb, BT, Cn, Cn);
    gemm_mfma<0, false><<<dim3(8, 64), blk, 0, stream>>>(vxb, WvT, vb, BT, Cn, Cn);
    gemm_mfma<2, true ><<<dim3(8, 64), blk, 0, stream>>>(gxb, WgT, gb, BT, Cn, Cn);
    // decay LoRA (f32)
    gemm_f32<1><<<dim3(1, 64), blk, 0, stream>>>(wxr, td_w1, wl1, BT, 64, Cn, nullptr);
    gemm_f32<3><<<dim3(16, 64), blk, 0, stream>>>(wl1, td_w2, lwb, BT, Cn, 64, t_dec);
    // chunked scan
    chunk_summary<<<dim3(Bn * Hn * NC), blk, 0, stream>>>(kb, vb, lwb, BcB, WtB);
    chunk_scan<<<dim3(Bn * Hn * 4), blk, 0, stream>>>(BcB, WtB, SbB);
    chunk_out<<<dim3(Bn * Hn * NC), blk, 0, stream>>>(rb, kb, vb, lwb, SbB, t_first, ybuf);
    // epilogue
    gn_mul<<<dim3(BT * Hn / 4), blk, 0, stream>>>(ybuf, gb, ln_w, ln_b, fin);
    gemm_mfma<0, false><<<dim3(8, 64), blk, 0, stream>>>(fin, WoT, out, BT, Cn, Cn);
}

// Round 4
// 447.357 us; speedup vs baseline: 4.0018x; 4.0018x over previous
//
#include <hip/hip_runtime.h>
#include <hip/hip_bf16.h>
#include <math.h>

// Problem constants
constexpr int Bn = 4, Tn = 1024, Cn = 1024, Hn = 16;
constexpr int BT = Bn * Tn;                 // 4096
constexpr long long BTC = (long long)BT * Cn;  // 4M elements
constexpr int CL = 64;                      // chunk length
constexpr int NC = Tn / CL;                 // 16 chunks

typedef __bf16 bf16x8_t __attribute__((ext_vector_type(8)));
typedef float f32x4_t __attribute__((ext_vector_type(4)));
typedef unsigned short us8_t __attribute__((ext_vector_type(8)));

// ---------------------------------------------------------------------------
// mix input for the token-mix LoRA: out = x + (x_prev - x)*x_maa[c]
// ---------------------------------------------------------------------------
__global__ __launch_bounds__(256) void prep_mixin(const float* __restrict__ x,
                                                  const float* __restrict__ x_maa,
                                                  float* __restrict__ out) {
    long long idx = (long long)blockIdx.x * 256 + threadIdx.x;
    if (idx >= BTC) return;
    int c  = (int)(idx & (Cn - 1));
    long long bt = idx >> 10;
    int t  = (int)(bt & (Tn - 1));
    float xv = x[idx];
    float xp = (t > 0) ? x[idx - Cn] : 0.f;
    out[idx] = xv + (xp - xv) * x_maa[c];
}

// ---------------------------------------------------------------------------
// Transpose + convert: W [R][Cc] f32 -> Wt [Cc][R] bf16
// ---------------------------------------------------------------------------
__global__ __launch_bounds__(256) void transp_bf16(const float* __restrict__ W,
                                                   __hip_bfloat16* __restrict__ Wt,
                                                   int R, int Cc) {
    __shared__ float tile[32][33];
    int c0 = blockIdx.x * 32, r0 = blockIdx.y * 32;
    int tx = threadIdx.x & 31, ty = threadIdx.x >> 5;
    #pragma unroll
    for (int i = 0; i < 4; i++)
        tile[ty + 8 * i][tx] = W[(size_t)(r0 + ty + 8 * i) * Cc + c0 + tx];
    __syncthreads();
    #pragma unroll
    for (int i = 0; i < 4; i++)
        Wt[(size_t)(c0 + ty + 8 * i) * R + r0 + tx] = __float2bfloat16(tile[tx][ty + 8 * i]);
}

// ---------------------------------------------------------------------------
// f32 tiled GEMM (small/odd shapes): C = A[M,K]@B[K,N].
// EPI: 1 tanh, 3 logdecay (-exp(extra[col]+acc))
// ---------------------------------------------------------------------------
template <int EPI>
__global__ __launch_bounds__(256) void gemm_f32(const float* __restrict__ A,
                                                const float* __restrict__ Bm,
                                                float* __restrict__ C,
                                                int M, int N, int K,
                                                const float* __restrict__ extra) {
    __shared__ float As[16][64];
    __shared__ float Bs[16][64];
    int tid = threadIdx.x;
    int m0 = blockIdx.y * 64, n0 = blockIdx.x * 64;
    int tx = tid & 15, ty = tid >> 4;
    int ar = tid >> 2, ac = (tid & 3) * 4;
    int br = tid >> 4, bc = (tid & 15) * 4;
    float acc[4][4] = {};

    for (int k0 = 0; k0 < K; k0 += 16) {
        const float* ap = A + (size_t)(m0 + ar) * K + k0 + ac;
        float4 av = *reinterpret_cast<const float4*>(ap);
        As[ac + 0][ar] = av.x; As[ac + 1][ar] = av.y;
        As[ac + 2][ar] = av.z; As[ac + 3][ar] = av.w;
        float4 bv;
        if (n0 + bc + 3 < N) {
            bv = *reinterpret_cast<const float4*>(Bm + (size_t)(k0 + br) * N + n0 + bc);
        } else {
            float tmp[4];
            #pragma unroll
            for (int i = 0; i < 4; i++) {
                int col = n0 + bc + i;
                tmp[i] = (col < N) ? Bm[(size_t)(k0 + br) * N + col] : 0.f;
            }
            bv = make_float4(tmp[0], tmp[1], tmp[2], tmp[3]);
        }
        *reinterpret_cast<float4*>(&Bs[br][bc]) = bv;
        __syncthreads();
        #pragma unroll
        for (int kk = 0; kk < 16; kk++) {
            float4 a4 = *reinterpret_cast<const float4*>(&As[kk][ty * 4]);
            float4 b4 = *reinterpret_cast<const float4*>(&Bs[kk][tx * 4]);
            float aa[4] = {a4.x, a4.y, a4.z, a4.w};
            float bb[4] = {b4.x, b4.y, b4.z, b4.w};
            #pragma unroll
            for (int i = 0; i < 4; i++)
                #pragma unroll
                for (int j = 0; j < 4; j++)
                    acc[i][j] = fmaf(aa[i], bb[j], acc[i][j]);
        }
        __syncthreads();
    }

    #pragma unroll
    for (int i = 0; i < 4; i++) {
        int row = m0 + ty * 4 + i;
        #pragma unroll
        for (int j = 0; j < 4; j++) {
            int col = n0 + tx * 4 + j;
            if (col < N) {
                float v = acc[i][j];
                if (EPI == 1) v = tanhf(v);
                else if (EPI == 3) v = -expf(extra[col] + v);
                C[(size_t)row * N + col] = v;
            }
        }
    }
}

// ---------------------------------------------------------------------------
// bf16 MFMA GEMM: C[M,N] = A[M,K] @ Bt[N,K]^T.  BM=64, BN=128, BK=64.
// 4 waves (2x2), wave tile 32x64, 16x16x32 MFMA, XOR-swizzled LDS.
// EPI: 0 none, 2 silu.  OBF16: write bf16 output.
// ---------------------------------------------------------------------------
template <int EPI, bool OBF16>
__global__ __launch_bounds__(256) void gemm_mfma(const __hip_bfloat16* __restrict__ A,
                                                 const __hip_bfloat16* __restrict__ Bt,
                                                 void* __restrict__ Cout,
                                                 int M, int N, int K) {
    __shared__ alignas(16) unsigned short As[64 * 64];
    __shared__ alignas(16) unsigned short Bs[128 * 64];
    int tid = threadIdx.x;
    int m0 = blockIdx.y * 64, n0 = blockIdx.x * 128;
    int wave = tid >> 6, lane = tid & 63;
    int wm = (wave & 1) * 32, wn = (wave >> 1) * 64;
    int l15 = lane & 15, l4 = lane >> 4;
    f32x4_t acc[2][4] = {};

    for (int k0 = 0; k0 < K; k0 += 64) {
        #pragma unroll
        for (int p = 0; p < 2; p++) {
            int cch = tid + p * 256;            // 0..511
            int row = cch >> 3, slot = cch & 7;
            int s2 = slot ^ (row & 7);
            *reinterpret_cast<us8_t*>(&As[row * 64 + s2 * 8]) =
                *reinterpret_cast<const us8_t*>(&A[(size_t)(m0 + row) * K + k0 + slot * 8]);
        }
        #pragma unroll
        for (int p = 0; p < 4; p++) {
            int cch = tid + p * 256;            // 0..1023
            int row = cch >> 3, slot = cch & 7;
            int s2 = slot ^ (row & 7);
            *reinterpret_cast<us8_t*>(&Bs[row * 64 + s2 * 8]) =
                *reinterpret_cast<const us8_t*>(&Bt[(size_t)(n0 + row) * K + k0 + slot * 8]);
        }
        __syncthreads();
        #pragma unroll
        for (int kw = 0; kw < 2; kw++) {
            int slot = kw * 4 + l4;
            bf16x8_t af[2], bfr[4];
            #pragma unroll
            for (int f = 0; f < 2; f++) {
                int ar = wm + f * 16 + l15;
                af[f] = *reinterpret_cast<const bf16x8_t*>(&As[ar * 64 + (slot ^ (ar & 7)) * 8]);
            }
            #pragma unroll
            for (int f = 0; f < 4; f++) {
                int br = wn + f * 16 + l15;
                bfr[f] = *reinterpret_cast<const bf16x8_t*>(&Bs[br * 64 + (slot ^ (br & 7)) * 8]);
            }
            #pragma unroll
            for (int i = 0; i < 2; i++)
                #pragma unroll
                for (int j = 0; j < 4; j++)
                    acc[i][j] = __builtin_amdgcn_mfma_f32_16x16x32_bf16(af[i], bfr[j], acc[i][j], 0, 0, 0);
        }
        __syncthreads();
    }

    #pragma unroll
    for (int i = 0; i < 2; i++) {
        int rbase = m0 + wm + i * 16 + l4 * 4;
        #pragma unroll
        for (int j = 0; j < 4; j++) {
            int col = n0 + wn + j * 16 + l15;
            #pragma unroll
            for (int q = 0; q < 4; q++) {
                float v = acc[i][j][q];
                if (EPI == 2) v = v / (1.f + expf(-v));
                size_t o = (size_t)(rbase + q) * N + col;
                if (OBF16) ((__hip_bfloat16*)Cout)[o] = __float2bfloat16(v);
                else       ((float*)Cout)[o] = v;
            }
        }
    }
}

// ---------------------------------------------------------------------------
// 5 mix deltas fused with wx/kx/vx/rx/gx build. Block = 8 bt-rows x 256 cols.
// Per-f restructure: only acc[8] live in the inner loop; each f's output is
// written immediately (short address live ranges; no spills).
// ---------------------------------------------------------------------------
__global__ __launch_bounds__(256) void deltas_mix(const float* __restrict__ x,
                                                  const float* __restrict__ mix160,
                                                  const float* __restrict__ w2,
                                                  const float* __restrict__ wmaa,
                                                  const float* __restrict__ kmaa,
                                                  const float* __restrict__ vmaa,
                                                  const float* __restrict__ rmaa,
                                                  const float* __restrict__ gmaa,
                                                  float* __restrict__ wx,
                                                  __hip_bfloat16* __restrict__ kxb,
                                                  __hip_bfloat16* __restrict__ vxb,
                                                  __hip_bfloat16* __restrict__ rxb,
                                                  __hip_bfloat16* __restrict__ gxb) {
    int tid = threadIdx.x;
    int c = blockIdx.x * 256 + tid;
    int r0 = blockIdx.y * 8;
    __shared__ float m[8][160];
    for (int i = tid; i < 1280; i += 256)
        m[i / 160][i % 160] = mix160[(size_t)(r0 + i / 160) * 160 + (i % 160)];
    __syncthreads();
    // Load x rows once; keep xv/sx in registers across the 5 f-passes.
    float xv[8], sx[8];
    #pragma unroll
    for (int r = 0; r < 8; r++) {
        int row = r0 + r;
        int t = row & (Tn - 1);
        size_t idx = (size_t)row * Cn + c;
        float xvv = x[idx];
        float xp = (t > 0) ? x[idx - Cn] : 0.f;
        xv[r] = xvv;
        sx[r] = xp - xvv;
    }
    #pragma unroll
    for (int f = 0; f < 5; f++) {
        float acc[8];
        #pragma unroll
        for (int r = 0; r < 8; r++) acc[r] = 0.f;
        for (int dd = 0; dd < 32; dd++) {
            float wv = w2[(size_t)(f * 32 + dd) * Cn + c];
            #pragma unroll
            for (int r = 0; r < 8; r++)
                acc[r] = fmaf(m[r][f * 32 + dd], wv, acc[r]);
        }
        const float* maa = (f == 0) ? wmaa : (f == 1) ? kmaa : (f == 2) ? vmaa
                         : (f == 3) ? rmaa : gmaa;
        float mv = maa[c];
        #pragma unroll
        for (int r = 0; r < 8; r++) {
            size_t idx = (size_t)(r0 + r) * Cn + c;
            float val = xv[r] + sx[r] * (mv + acc[r]);
            if (f == 0)      wx[idx]  = val;
            else if (f == 1) kxb[idx] = __float2bfloat16(val);
            else if (f == 2) vxb[idx] = __float2bfloat16(val);
            else if (f == 3) rxb[idx] = __float2bfloat16(val);
            else             gxb[idx] = __float2bfloat16(val);
        }
    }
}

// ---------------------------------------------------------------------------
// Chunked WKV stage A: per (b,h,chunk):
//   Wtot[ch] = exp(sum lw); Bc[k][v] = sum_tau exp(Lend-Linc[tau])*k*v
// ---------------------------------------------------------------------------
__global__ __launch_bounds__(256) void chunk_summary(const float* __restrict__ kb,
                                                     const float* __restrict__ vb,
                                                     const float* __restrict__ lw,
                                                     float* __restrict__ Bc,
                                                     float* __restrict__ Wtot) {
    int bid = blockIdx.x;
    int c = bid & 15, h = (bid >> 4) & 15, b = bid >> 8;
    size_t gbase = ((size_t)(b * Tn + c * CL) * Hn + h) * 64;
    int tid = threadIdx.x;
    __shared__ float linc[64][68];
    __shared__ float kd[64][68];
    __shared__ float vs[64][68];
    __shared__ float wtp[4][64];
    int wave = tid >> 6, lane = tid & 63;
    {
        float acc = 0.f;
        #pragma unroll
        for (int i = 0; i < 16; i++) {
            int t = wave * 16 + i;
            acc += lw[gbase + (size_t)t * 1024 + lane];
            linc[t][lane] = acc;
        }
        wtp[wave][lane] = acc;
    }
    __syncthreads();
    {
        float off = 0.f;
        for (int g = 0; g < wave; g++) off += wtp[g][lane];
        #pragma unroll
        for (int i = 0; i < 16; i++) linc[wave * 16 + i][lane] += off;
    }
    __syncthreads();
    int t4 = tid >> 2, c0 = (tid & 3) * 16;
    #pragma unroll
    for (int i = 0; i < 4; i++) {
        int ch = c0 + i * 4;
        size_t ga = gbase + (size_t)t4 * 1024 + ch;
        float4 k4 = *reinterpret_cast<const float4*>(kb + ga);
        float4 v4 = *reinterpret_cast<const float4*>(vb + ga);
        float kk[4] = {k4.x, k4.y, k4.z, k4.w};
        float vv[4] = {v4.x, v4.y, v4.z, v4.w};
        #pragma unroll
        for (int j = 0; j < 4; j++) {
            float li = linc[t4][ch + j];
            float lend = linc[63][ch + j];
            kd[t4][ch + j] = kk[j] * expf(lend - li);
            vs[t4][ch + j] = vv[j];
        }
    }
    if (tid < 64) Wtot[(size_t)bid * 64 + tid] = expf(linc[63][tid]);
    __syncthreads();
    int kk = tid >> 2, v0 = (tid & 3) * 16;
    float4 o[4] = {};
    for (int tau = 0; tau < 64; tau++) {
        float kdv = kd[tau][kk];
        #pragma unroll
        for (int j = 0; j < 4; j++) {
            float4 v4 = *reinterpret_cast<const float4*>(&vs[tau][v0 + 4 * j]);
            o[j].x = fmaf(kdv, v4.x, o[j].x);
            o[j].y = fmaf(kdv, v4.y, o[j].y);
            o[j].z = fmaf(kdv, v4.z, o[j].z);
            o[j].w = fmaf(kdv, v4.w, o[j].w);
        }
    }
    #pragma unroll
    for (int j = 0; j < 4; j++)
        *reinterpret_cast<float4*>(Bc + (size_t)bid * 4096 + kk * 64 + v0 + 4 * j) = o[j];
}

// ---------------------------------------------------------------------------
// Stage B: sequential scan over NC=16 chunk states (entry states out).
// ---------------------------------------------------------------------------
__global__ __launch_bounds__(256) void chunk_scan(const float* __restrict__ Bc,
                                                  const float* __restrict__ Wtot,
                                                  float* __restrict__ Sbuf) {
    int bid = blockIdx.x;
    int bh = bid >> 2, vg = bid & 3;
    int kk = threadIdx.x >> 2;
    int v = vg * 16 + (threadIdx.x & 3) * 4;
    float4 S = make_float4(0.f, 0.f, 0.f, 0.f);
    for (int c = 0; c < NC; c++) {
        size_t cb = (size_t)(bh * NC + c) * 4096 + (size_t)kk * 64 + v;
        *reinterpret_cast<float4*>(Sbuf + cb) = S;
        float wt = Wtot[(size_t)(bh * NC + c) * 64 + kk];
        float4 b4 = *reinterpret_cast<const float4*>(Bc + cb);
        S.x = fmaf(wt, S.x, b4.x);
        S.y = fmaf(wt, S.y, b4.y);
        S.z = fmaf(wt, S.z, b4.z);
        S.w = fmaf(wt, S.w, b4.w);
    }
}

// ---------------------------------------------------------------------------
// Stage C: per (b,h,chunk) outputs (recomputes Linc prefix in LDS):
//   Y = mask(Q'K'^T + diag(r.u.k)) @ V + Q' @ S_entry
// ---------------------------------------------------------------------------
__global__ __launch_bounds__(256) void chunk_out(const float* __restrict__ rb,
                                                 const float* __restrict__ kb,
                                                 const float* __restrict__ vb,
                                                 const float* __restrict__ lw,
                                                 const float* __restrict__ Sbuf,
                                                 const float* __restrict__ tf,
                                                 float* __restrict__ y) {
    int bid = blockIdx.x;
    int c = bid & 15, h = (bid >> 4) & 15, b = bid >> 8;
    size_t gbase = ((size_t)(b * Tn + c * CL) * Hn + h) * 64;
    int tid = threadIdx.x;
    __shared__ float qs[64][68], ks[64][68], vs[64][68], as_[64][68], sc[64][68];
    __shared__ float wtp[4][64];
    __shared__ float diag[64];
    int wave = tid >> 6, lane = tid & 63;
    // prefix sums of lw -> as_ (used as linc scratch)
    {
        float acc = 0.f;
        #pragma unroll
        for (int i = 0; i < 16; i++) {
            int t = wave * 16 + i;
            acc += lw[gbase + (size_t)t * 1024 + lane];
            as_[t][lane] = acc;
        }
        wtp[wave][lane] = acc;
    }
    __syncthreads();
    {
        float off = 0.f;
        for (int g = 0; g < wave; g++) off += wtp[g][lane];
        #pragma unroll
        for (int i = 0; i < 16; i++) as_[wave * 16 + i][lane] += off;
    }
    __syncthreads();
    int t = tid >> 2, c0 = (tid & 3) * 16;
    float dpart = 0.f;
    #pragma unroll
    for (int i = 0; i < 4; i++) {
        int ch = c0 + i * 4;
        size_t ga = gbase + (size_t)t * 1024 + ch;
        float4 r4 = *reinterpret_cast<const float4*>(rb + ga);
        float4 k4 = *reinterpret_cast<const float4*>(kb + ga);
        float4 v4 = *reinterpret_cast<const float4*>(vb + ga);
        float4 l4 = *reinterpret_cast<const float4*>(lw + ga);
        float4 li4 = *reinterpret_cast<const float4*>(&as_[t][ch]);
        float4 u4 = *reinterpret_cast<const float4*>(tf + h * 64 + ch);
        float rr[4] = {r4.x, r4.y, r4.z, r4.w};
        float kkv[4] = {k4.x, k4.y, k4.z, k4.w};
        float vv[4] = {v4.x, v4.y, v4.z, v4.w};
        float lwv[4] = {l4.x, l4.y, l4.z, l4.w};
        float li[4] = {li4.x, li4.y, li4.z, li4.w};
        float uu[4] = {u4.x, u4.y, u4.z, u4.w};
        #pragma unroll
        for (int j = 0; j < 4; j++) {
            qs[t][ch + j] = rr[j] * expf(li[j] - lwv[j]);  // exp(Lexc)
            ks[t][ch + j] = kkv[j] * expf(-li[j]);
            vs[t][ch + j] = vv[j];
            dpart = fmaf(rr[j] * uu[j], kkv[j], dpart);
        }
        float4 s4 = *reinterpret_cast<const float4*>(Sbuf + (size_t)bid * 4096 + t * 64 + ch);
        *reinterpret_cast<float4*>(&sc[t][ch]) = s4;
    }
    dpart += __shfl_xor(dpart, 1);
    dpart += __shfl_xor(dpart, 2);
    if ((tid & 3) == 0) diag[t] = dpart;
    __syncthreads();
    {
        int tj = tid & 3;
        float acc[16];
        #pragma unroll
        for (int i = 0; i < 16; i++) acc[i] = 0.f;
        for (int ch = 0; ch < 64; ch += 4) {
            float4 q4 = *reinterpret_cast<const float4*>(&qs[t][ch]);
            #pragma unroll
            for (int i = 0; i < 16; i++) {
                int tau = tj + 4 * i;
                if (tau < t) {
                    float4 k4 = *reinterpret_cast<const float4*>(&ks[tau][ch]);
                    acc[i] += q4.x * k4.x + q4.y * k4.y + q4.z * k4.z + q4.w * k4.w;
                }
            }
        }
        #pragma unroll
        for (int i = 0; i < 16; i++) {
            int tau = tj + 4 * i;
            as_[t][tau] = (tau < t) ? acc[i] : (tau == t ? diag[t] : 0.f);
        }
    }
    __syncthreads();
    int v0 = (tid & 3) * 16;
    float4 o[4] = {};
    for (int tau = 0; tau <= t; tau++) {
        float av = as_[t][tau];
        #pragma unroll
        for (int j = 0; j < 4; j++) {
            float4 v4 = *reinterpret_cast<const float4*>(&vs[tau][v0 + 4 * j]);
            o[j].x = fmaf(av, v4.x, o[j].x);
            o[j].y = fmaf(av, v4.y, o[j].y);
            o[j].z = fmaf(av, v4.z, o[j].z);
            o[j].w = fmaf(av, v4.w, o[j].w);
        }
    }
    for (int k = 0; k < 64; k++) {
        float qv = qs[t][k];
        #pragma unroll
        for (int j = 0; j < 4; j++) {
            float4 s4 = *reinterpret_cast<const float4*>(&sc[k][v0 + 4 * j]);
            o[j].x = fmaf(qv, s4.x, o[j].x);
            o[j].y = fmaf(qv, s4.y, o[j].y);
            o[j].z = fmaf(qv, s4.z, o[j].z);
            o[j].w = fmaf(qv, s4.w, o[j].w);
        }
    }
    #pragma unroll
    for (int j = 0; j < 4; j++)
        *reinterpret_cast<float4*>(y + gbase + (size_t)t * 1024 + v0 + 4 * j) = o[j];
}

// ---------------------------------------------------------------------------
// GroupNorm per (bt,h) over 64 channels (after /8), *ln_w + ln_b, then *g.
// Output bf16 (feeds Wo MFMA GEMM).
// ---------------------------------------------------------------------------
__global__ __launch_bounds__(256) void gn_mul(const float* __restrict__ y,
                                              const __hip_bfloat16* __restrict__ g,
                                              const float* __restrict__ lnw,
                                              const float* __restrict__ lnb,
                                              __hip_bfloat16* __restrict__ fin) {
    int tid = threadIdx.x;
    int lane = tid & 63;
    int wv = tid >> 6;
    int grp = blockIdx.x * 4 + wv;    // bt*16 + h
    int h = grp & 15;
    size_t idx = (size_t)grp * 64 + lane;
    float val = y[idx] * 0.125f;
    float sum = val, sq = val * val;
    #pragma unroll
    for (int off = 32; off > 0; off >>= 1) {
        sum += __shfl_xor(sum, off, 64);
        sq  += __shfl_xor(sq,  off, 64);
    }
    float mu = sum * (1.f / 64.f);
    float var = sq * (1.f / 64.f) - mu * mu;
    float rs = rsqrtf(var + 1e-5f);
    float o = (val - mu) * rs * lnw[h * 64 + lane] + lnb[h * 64 + lane];
    fin[idx] = __float2bfloat16(o * __bfloat162float(g[idx]));
}

// ---------------------------------------------------------------------------
extern "C" void kernel_launch(void* const* d_in, const int* in_sizes, int n_in,
                              void* d_out, int out_size, void* d_ws, size_t ws_size,
                              hipStream_t stream) {
    (void)in_sizes; (void)n_in; (void)out_size; (void)ws_size;
    const float* x      = (const float*)d_in[0];
    const float* x_maa  = (const float*)d_in[1];
    const float* w_maa  = (const float*)d_in[2];
    const float* k_maa  = (const float*)d_in[3];
    const float* v_maa  = (const float*)d_in[4];
    const float* r_maa  = (const float*)d_in[5];
    const float* g_maa  = (const float*)d_in[6];
    const float* tm_w1  = (const float*)d_in[7];
    const float* tm_w2  = (const float*)d_in[8];
    const float* td_w1  = (const float*)d_in[9];
    const float* td_w2  = (const float*)d_in[10];
    const float* t_dec  = (const float*)d_in[11];
    const float* t_first= (const float*)d_in[12];
    const float* Wr     = (const float*)d_in[13];
    const float* Wk     = (const float*)d_in[14];
    const float* Wv     = (const float*)d_in[15];
    const float* Wg     = (const float*)d_in[16];
    const float* Wo     = (const float*)d_in[17];
    const float* ln_w   = (const float*)d_in[18];
    const float* ln_b   = (const float*)d_in[19];
    float* out = (float*)d_out;

    // Byte allocator, 256B aligned
    char* ws = (char*)d_ws;
    size_t off = 0;
    auto alloc = [&](size_t bytes) -> void* {
        void* p = ws + off;
        off = (off + bytes + 255) & ~(size_t)255;
        return p;
    };
    float* mixin  = (float*)alloc(BTC * 4);            // alias: rb
    float* mix160 = (float*)alloc((size_t)BT * 160 * 4);
    float* wxr    = (float*)alloc(BTC * 4);            // wx -> BcB -> ybuf
    __hip_bfloat16* kxb = (__hip_bfloat16*)alloc(BTC * 2);  // alias: fin
    __hip_bfloat16* vxb = (__hip_bfloat16*)alloc(BTC * 2);
    __hip_bfloat16* rxb = (__hip_bfloat16*)alloc(BTC * 2);  // rxb+gxb -> SbB (16MB)
    __hip_bfloat16* gxb = (__hip_bfloat16*)alloc(BTC * 2);
    float* kb  = (float*)alloc(BTC * 4);
    float* vb  = (float*)alloc(BTC * 4);
    __hip_bfloat16* gb = (__hip_bfloat16*)alloc(BTC * 2);
    float* wl1 = (float*)alloc((size_t)BT * 64 * 4);   // alias: WtB
    float* lwb = (float*)alloc(BTC * 4);
    __hip_bfloat16* WrT = (__hip_bfloat16*)alloc((size_t)Cn * Cn * 2);
    __hip_bfloat16* WkT = (__hip_bfloat16*)alloc((size_t)Cn * Cn * 2);
    __hip_bfloat16* WvT = (__hip_bfloat16*)alloc((size_t)Cn * Cn * 2);
    __hip_bfloat16* WgT = (__hip_bfloat16*)alloc((size_t)Cn * Cn * 2);
    __hip_bfloat16* WoT = (__hip_bfloat16*)alloc((size_t)Cn * Cn * 2);
    // Aliases (stream-ordered; producers complete before reuse):
    float* rb   = mixin;           // r projection (mixin dead after LoRA1)
    float* BcB  = wxr;             // chunk contributions (wx dead after wl1 GEMM)
    float* ybuf = wxr;             // recurrence out (BcB dead after chunk_scan)
    float* WtB  = wl1;             // chunk decay totals (wl1 dead after decay GEMM)
    float* SbB  = (float*)rxb;     // entry states, spans rxb+gxb (dead after projections)
    __hip_bfloat16* fin = kxb;     // gn output (kxb dead after k projection)

    dim3 blk(256);
    // weight transpose+convert
    transp_bf16<<<dim3(32, 32), blk, 0, stream>>>(Wr, WrT, Cn, Cn);
    transp_bf16<<<dim3(32, 32), blk, 0, stream>>>(Wk, WkT, Cn, Cn);
    transp_bf16<<<dim3(32, 32), blk, 0, stream>>>(Wv, WvT, Cn, Cn);
    transp_bf16<<<dim3(32, 32), blk, 0, stream>>>(Wg, WgT, Cn, Cn);
    transp_bf16<<<dim3(32, 32), blk, 0, stream>>>(Wo, WoT, Cn, Cn);
    // token-mix LoRA
    prep_mixin<<<dim3((unsigned)((BTC + 255) / 256)), blk, 0, stream>>>(x, x_maa, mixin);
    gemm_f32<1><<<dim3(3, 64), blk, 0, stream>>>(mixin, tm_w1, mix160, BT, 160, Cn, nullptr);
    deltas_mix<<<dim3(4, 512), blk, 0, stream>>>(x, mix160, tm_w2,
                                                 w_maa, k_maa, v_maa, r_maa, g_maa,
                                                 wxr, kxb, vxb, rxb, gxb);
    // projections (bf16 MFMA)
    gemm_mfma<0, false><<<dim3(8, 64), blk, 0, stream>>>(rxb, WrT, rb, BT, Cn, Cn);
    gemm_mfma<0, false><<<dim3(8, 64), blk, 0, stream>>>(kxb, WkT, kb, BT, Cn, Cn);
    gemm_mfma<0, false><<<dim3(8, 64), blk, 0, stream>>>(vxb, WvT, vb, BT, Cn, Cn);
    gemm_mfma<2, true ><<<dim3(8, 64), blk, 0, stream>>>(gxb, WgT, gb, BT, Cn, Cn);
    // decay LoRA (f32)
    gemm_f32<1><<<dim3(1, 64), blk, 0, stream>>>(wxr, td_w1, wl1, BT, 64, Cn, nullptr);
    gemm_f32<3><<<dim3(16, 64), blk, 0, stream>>>(wl1, td_w2, lwb, BT, Cn, 64, t_dec);
    // chunked scan
    chunk_summary<<<dim3(Bn * Hn * NC), blk, 0, stream>>>(kb, vb, lwb, BcB, WtB);
    chunk_scan<<<dim3(Bn * Hn * 4), blk, 0, stream>>>(BcB, WtB, SbB);
    chunk_out<<<dim3(Bn * Hn * NC), blk, 0, stream>>>(rb, kb, vb, lwb, SbB, t_first, ybuf);
    // epilogue
    gn_mul<<<dim3(BT * Hn / 4), blk, 0, stream>>>(ybuf, gb, ln_w, ln_b, fin);
    gemm_mfma<0, false><<<dim3(8, 64), blk, 0, stream>>>(fin, WoT, out, BT, Cn, Cn);
}

// Round 5
// 323.464 us; speedup vs baseline: 5.5345x; 1.3830x over previous
//
#include <hip/hip_runtime.h>
#include <hip/hip_bf16.h>
#include <math.h>

// Problem constants
constexpr int Bn = 4, Tn = 1024, Cn = 1024, Hn = 16;
constexpr int BT = Bn * Tn;                 // 4096
constexpr long long BTC = (long long)BT * Cn;  // 4M elements
constexpr int CL = 64;                      // chunk length
constexpr int NC = Tn / CL;                 // 16 chunks

typedef __bf16 bf16x8_t __attribute__((ext_vector_type(8)));
typedef float f32x4_t __attribute__((ext_vector_type(4)));
typedef unsigned short us8_t __attribute__((ext_vector_type(8)));

// ---------------------------------------------------------------------------
// mix input for the token-mix LoRA: out = bf16(x + (x_prev - x)*x_maa[c])
// ---------------------------------------------------------------------------
__global__ __launch_bounds__(256) void prep_mixin(const float* __restrict__ x,
                                                  const float* __restrict__ x_maa,
                                                  __hip_bfloat16* __restrict__ out) {
    long long idx = (long long)blockIdx.x * 256 + threadIdx.x;
    if (idx >= BTC) return;
    int c  = (int)(idx & (Cn - 1));
    long long bt = idx >> 10;
    int t  = (int)(bt & (Tn - 1));
    float xv = x[idx];
    float xp = (t > 0) ? x[idx - Cn] : 0.f;
    out[idx] = __float2bfloat16(xv + (xp - xv) * x_maa[c]);
}

// ---------------------------------------------------------------------------
// Transpose + convert: W [R][Cc] f32 -> Wt [Cc][R] bf16  (R, Cc multiples of 32)
// ---------------------------------------------------------------------------
__global__ __launch_bounds__(256) void transp_bf16(const float* __restrict__ W,
                                                   __hip_bfloat16* __restrict__ Wt,
                                                   int R, int Cc) {
    __shared__ float tile[32][33];
    int c0 = blockIdx.x * 32, r0 = blockIdx.y * 32;
    int tx = threadIdx.x & 31, ty = threadIdx.x >> 5;
    #pragma unroll
    for (int i = 0; i < 4; i++)
        tile[ty + 8 * i][tx] = W[(size_t)(r0 + ty + 8 * i) * Cc + c0 + tx];
    __syncthreads();
    #pragma unroll
    for (int i = 0; i < 4; i++)
        Wt[(size_t)(c0 + ty + 8 * i) * R + r0 + tx] = __float2bfloat16(tile[tx][ty + 8 * i]);
}

// ---------------------------------------------------------------------------
// f32 tiled GEMM (decay LoRA path, precision-sensitive): C = A[M,K]@B[K,N].
// EPI: 1 tanh, 3 logdecay (-exp(extra[col]+acc))
// ---------------------------------------------------------------------------
template <int EPI>
__global__ __launch_bounds__(256) void gemm_f32(const float* __restrict__ A,
                                                const float* __restrict__ Bm,
                                                float* __restrict__ C,
                                                int M, int N, int K,
                                                const float* __restrict__ extra) {
    __shared__ float As[16][64];
    __shared__ float Bs[16][64];
    int tid = threadIdx.x;
    int m0 = blockIdx.y * 64, n0 = blockIdx.x * 64;
    int tx = tid & 15, ty = tid >> 4;
    int ar = tid >> 2, ac = (tid & 3) * 4;
    int br = tid >> 4, bc = (tid & 15) * 4;
    float acc[4][4] = {};

    for (int k0 = 0; k0 < K; k0 += 16) {
        const float* ap = A + (size_t)(m0 + ar) * K + k0 + ac;
        float4 av = *reinterpret_cast<const float4*>(ap);
        As[ac + 0][ar] = av.x; As[ac + 1][ar] = av.y;
        As[ac + 2][ar] = av.z; As[ac + 3][ar] = av.w;
        float4 bv;
        if (n0 + bc + 3 < N) {
            bv = *reinterpret_cast<const float4*>(Bm + (size_t)(k0 + br) * N + n0 + bc);
        } else {
            float tmp[4];
            #pragma unroll
            for (int i = 0; i < 4; i++) {
                int col = n0 + bc + i;
                tmp[i] = (col < N) ? Bm[(size_t)(k0 + br) * N + col] : 0.f;
            }
            bv = make_float4(tmp[0], tmp[1], tmp[2], tmp[3]);
        }
        *reinterpret_cast<float4*>(&Bs[br][bc]) = bv;
        __syncthreads();
        #pragma unroll
        for (int kk = 0; kk < 16; kk++) {
            float4 a4 = *reinterpret_cast<const float4*>(&As[kk][ty * 4]);
            float4 b4 = *reinterpret_cast<const float4*>(&Bs[kk][tx * 4]);
            float aa[4] = {a4.x, a4.y, a4.z, a4.w};
            float bb[4] = {b4.x, b4.y, b4.z, b4.w};
            #pragma unroll
            for (int i = 0; i < 4; i++)
                #pragma unroll
                for (int j = 0; j < 4; j++)
                    acc[i][j] = fmaf(aa[i], bb[j], acc[i][j]);
        }
        __syncthreads();
    }

    #pragma unroll
    for (int i = 0; i < 4; i++) {
        int row = m0 + ty * 4 + i;
        #pragma unroll
        for (int j = 0; j < 4; j++) {
            int col = n0 + tx * 4 + j;
            if (col < N) {
                float v = acc[i][j];
                if (EPI == 1) v = tanhf(v);
                else if (EPI == 3) v = -expf(extra[col] + v);
                C[(size_t)row * N + col] = v;
            }
        }
    }
}

// ---------------------------------------------------------------------------
// bf16 MFMA GEMM: C[M,N] = A[M,K] @ Bt[N,K]^T.  BM=64, BN=128, BK=64.
// 4 waves (2x2), wave tile 32x64, 16x16x32 MFMA, XOR-swizzled LDS.
// N-guarded (tile-clamped B rows, guarded epilogue). M%64==0, K%64==0.
// EPI: 0 none, 1 tanh, 2 silu.  OBF16: write bf16 output.
// ---------------------------------------------------------------------------
template <int EPI, bool OBF16>
__global__ __launch_bounds__(256) void gemm_mfma(const __hip_bfloat16* __restrict__ A,
                                                 const __hip_bfloat16* __restrict__ Bt,
                                                 void* __restrict__ Cout,
                                                 int M, int N, int K) {
    __shared__ alignas(16) unsigned short As[64 * 64];
    __shared__ alignas(16) unsigned short Bs[128 * 64];
    int tid = threadIdx.x;
    int m0 = blockIdx.y * 64, n0 = blockIdx.x * 128;
    int wave = tid >> 6, lane = tid & 63;
    int wm = (wave & 1) * 32, wn = (wave >> 1) * 64;
    int l15 = lane & 15, l4 = lane >> 4;
    f32x4_t acc[2][4] = {};

    for (int k0 = 0; k0 < K; k0 += 64) {
        #pragma unroll
        for (int p = 0; p < 2; p++) {
            int cch = tid + p * 256;            // 0..511
            int row = cch >> 3, slot = cch & 7;
            int s2 = slot ^ (row & 7);
            *reinterpret_cast<us8_t*>(&As[row * 64 + s2 * 8]) =
                *reinterpret_cast<const us8_t*>(&A[(size_t)(m0 + row) * K + k0 + slot * 8]);
        }
        #pragma unroll
        for (int p = 0; p < 4; p++) {
            int cch = tid + p * 256;            // 0..1023
            int row = cch >> 3, slot = cch & 7;
            int s2 = slot ^ (row & 7);
            int rowg = n0 + row; if (rowg > N - 1) rowg = N - 1;  // clamp
            *reinterpret_cast<us8_t*>(&Bs[row * 64 + s2 * 8]) =
                *reinterpret_cast<const us8_t*>(&Bt[(size_t)rowg * K + k0 + slot * 8]);
        }
        __syncthreads();
        #pragma unroll
        for (int kw = 0; kw < 2; kw++) {
            int slot = kw * 4 + l4;
            bf16x8_t af[2], bfr[4];
            #pragma unroll
            for (int f = 0; f < 2; f++) {
                int ar = wm + f * 16 + l15;
                af[f] = *reinterpret_cast<const bf16x8_t*>(&As[ar * 64 + (slot ^ (ar & 7)) * 8]);
            }
            #pragma unroll
            for (int f = 0; f < 4; f++) {
                int br = wn + f * 16 + l15;
                bfr[f] = *reinterpret_cast<const bf16x8_t*>(&Bs[br * 64 + (slot ^ (br & 7)) * 8]);
            }
            #pragma unroll
            for (int i = 0; i < 2; i++)
                #pragma unroll
                for (int j = 0; j < 4; j++)
                    acc[i][j] = __builtin_amdgcn_mfma_f32_16x16x32_bf16(af[i], bfr[j], acc[i][j], 0, 0, 0);
        }
        __syncthreads();
    }

    #pragma unroll
    for (int i = 0; i < 2; i++) {
        int rbase = m0 + wm + i * 16 + l4 * 4;
        #pragma unroll
        for (int j = 0; j < 4; j++) {
            int col = n0 + wn + j * 16 + l15;
            if (col < N) {
                #pragma unroll
                for (int q = 0; q < 4; q++) {
                    float v = acc[i][j][q];
                    if (EPI == 1) v = tanhf(v);
                    else if (EPI == 2) v = v / (1.f + expf(-v));
                    size_t o = (size_t)(rbase + q) * N + col;
                    if (OBF16) ((__hip_bfloat16*)Cout)[o] = __float2bfloat16(v);
                    else       ((float*)Cout)[o] = v;
                }
            }
        }
    }
}

// ---------------------------------------------------------------------------
// 5 mix deltas fused with wx/kx/vx/rx/gx build. Block = 8 bt-rows x 256 cols.
// ---------------------------------------------------------------------------
__global__ __launch_bounds__(256) void deltas_mix(const float* __restrict__ x,
                                                  const float* __restrict__ mix160,
                                                  const float* __restrict__ w2,
                                                  const float* __restrict__ wmaa,
                                                  const float* __restrict__ kmaa,
                                                  const float* __restrict__ vmaa,
                                                  const float* __restrict__ rmaa,
                                                  const float* __restrict__ gmaa,
                                                  float* __restrict__ wx,
                                                  __hip_bfloat16* __restrict__ kxb,
                                                  __hip_bfloat16* __restrict__ vxb,
                                                  __hip_bfloat16* __restrict__ rxb,
                                                  __hip_bfloat16* __restrict__ gxb) {
    int tid = threadIdx.x;
    int c = blockIdx.x * 256 + tid;
    int r0 = blockIdx.y * 8;
    __shared__ float m[8][160];
    for (int i = tid; i < 1280; i += 256)
        m[i / 160][i % 160] = mix160[(size_t)(r0 + i / 160) * 160 + (i % 160)];
    __syncthreads();
    float xv[8], sx[8];
    #pragma unroll
    for (int r = 0; r < 8; r++) {
        int row = r0 + r;
        int t = row & (Tn - 1);
        size_t idx = (size_t)row * Cn + c;
        float xvv = x[idx];
        float xp = (t > 0) ? x[idx - Cn] : 0.f;
        xv[r] = xvv;
        sx[r] = xp - xvv;
    }
    #pragma unroll
    for (int f = 0; f < 5; f++) {
        float acc[8];
        #pragma unroll
        for (int r = 0; r < 8; r++) acc[r] = 0.f;
        for (int dd = 0; dd < 32; dd++) {
            float wv = w2[(size_t)(f * 32 + dd) * Cn + c];
            #pragma unroll
            for (int r = 0; r < 8; r++)
                acc[r] = fmaf(m[r][f * 32 + dd], wv, acc[r]);
        }
        const float* maa = (f == 0) ? wmaa : (f == 1) ? kmaa : (f == 2) ? vmaa
                         : (f == 3) ? rmaa : gmaa;
        float mv = maa[c];
        #pragma unroll
        for (int r = 0; r < 8; r++) {
            size_t idx = (size_t)(r0 + r) * Cn + c;
            float val = xv[r] + sx[r] * (mv + acc[r]);
            if (f == 0)      wx[idx]  = val;
            else if (f == 1) kxb[idx] = __float2bfloat16(val);
            else if (f == 2) vxb[idx] = __float2bfloat16(val);
            else if (f == 3) rxb[idx] = __float2bfloat16(val);
            else             gxb[idx] = __float2bfloat16(val);
        }
    }
}

// ---------------------------------------------------------------------------
// Chunked WKV stage A (MFMA): per (b,h,chunk):
//   Wtot[ch] = exp(sum lw); Bc[k][v] = sum_tau kd[tau][k]*vs[tau][v]
//   where kd = k*exp(Lend-Linc). Bc computed as kdT @ vsT^T via 16x16x32 MFMA.
// ---------------------------------------------------------------------------
__global__ __launch_bounds__(256) void chunk_summary(const float* __restrict__ kb,
                                                     const float* __restrict__ vb,
                                                     const float* __restrict__ lw,
                                                     float* __restrict__ Bc,
                                                     float* __restrict__ Wtot) {
    int bid = blockIdx.x;
    int c = bid & 15, h = (bid >> 4) & 15, b = bid >> 8;
    size_t gbase = ((size_t)(b * Tn + c * CL) * Hn + h) * 64;
    int tid = threadIdx.x;
    __shared__ float linc[64][68];
    __shared__ float wtp[4][64];
    __shared__ alignas(16) __hip_bfloat16 kdT[64][72];  // [ch][tau]
    __shared__ alignas(16) __hip_bfloat16 vsT[64][72];  // [v][tau]
    int wave = tid >> 6, lane = tid & 63;
    {
        float acc = 0.f;
        #pragma unroll
        for (int i = 0; i < 16; i++) {
            int t = wave * 16 + i;
            acc += lw[gbase + (size_t)t * 1024 + lane];
            linc[t][lane] = acc;
        }
        wtp[wave][lane] = acc;
    }
    __syncthreads();
    {
        float off = 0.f;
        for (int g = 0; g < wave; g++) off += wtp[g][lane];
        #pragma unroll
        for (int i = 0; i < 16; i++) linc[wave * 16 + i][lane] += off;
    }
    __syncthreads();
    int t4 = tid >> 2, c0 = (tid & 3) * 16;
    #pragma unroll
    for (int i = 0; i < 4; i++) {
        int ch = c0 + i * 4;
        size_t ga = gbase + (size_t)t4 * 1024 + ch;
        float4 k4 = *reinterpret_cast<const float4*>(kb + ga);
        float4 v4 = *reinterpret_cast<const float4*>(vb + ga);
        float kk[4] = {k4.x, k4.y, k4.z, k4.w};
        float vv[4] = {v4.x, v4.y, v4.z, v4.w};
        #pragma unroll
        for (int j = 0; j < 4; j++) {
            float li = linc[t4][ch + j];
            float lend = linc[63][ch + j];
            kdT[ch + j][t4] = __float2bfloat16(kk[j] * expf(lend - li));
            vsT[ch + j][t4] = __float2bfloat16(vv[j]);
        }
    }
    if (tid < 64) Wtot[(size_t)bid * 64 + tid] = expf(linc[63][tid]);
    __syncthreads();
    // MFMA: wave owns k-rows [wave*16, wave*16+16)
    int l15 = lane & 15, l4q = lane >> 4;
    #pragma unroll
    for (int nt = 0; nt < 4; nt++) {
        f32x4_t acc = {};
        #pragma unroll
        for (int kt = 0; kt < 2; kt++) {
            bf16x8_t a = *reinterpret_cast<const bf16x8_t*>(&kdT[wave * 16 + l15][kt * 32 + l4q * 8]);
            bf16x8_t bb = *reinterpret_cast<const bf16x8_t*>(&vsT[nt * 16 + l15][kt * 32 + l4q * 8]);
            acc = __builtin_amdgcn_mfma_f32_16x16x32_bf16(a, bb, acc, 0, 0, 0);
        }
        #pragma unroll
        for (int q = 0; q < 4; q++) {
            int krow = wave * 16 + l4q * 4 + q;
            Bc[(size_t)bid * 4096 + (size_t)krow * 64 + nt * 16 + l15] = acc[q];
        }
    }
}

// ---------------------------------------------------------------------------
// Stage B: sequential scan over NC=16 chunk states; writes TRANSPOSED entry
// states SbufT[v][k] (feeds chunk_out's B-operand directly).
// ---------------------------------------------------------------------------
__global__ __launch_bounds__(256) void chunk_scan(const float* __restrict__ Bc,
                                                  const float* __restrict__ Wtot,
                                                  float* __restrict__ SbufT) {
    int bid = blockIdx.x;
    int bh = bid >> 2, vg = bid & 3;
    int kk = threadIdx.x >> 2;
    int v = vg * 16 + (threadIdx.x & 3) * 4;
    float4 S = make_float4(0.f, 0.f, 0.f, 0.f);
    for (int c = 0; c < NC; c++) {
        size_t base = (size_t)(bh * NC + c) * 4096;
        SbufT[base + (size_t)(v + 0) * 64 + kk] = S.x;
        SbufT[base + (size_t)(v + 1) * 64 + kk] = S.y;
        SbufT[base + (size_t)(v + 2) * 64 + kk] = S.z;
        SbufT[base + (size_t)(v + 3) * 64 + kk] = S.w;
        float wt = Wtot[(size_t)(bh * NC + c) * 64 + kk];
        float4 b4 = *reinterpret_cast<const float4*>(Bc + base + (size_t)kk * 64 + v);
        S.x = fmaf(wt, S.x, b4.x);
        S.y = fmaf(wt, S.y, b4.y);
        S.z = fmaf(wt, S.z, b4.z);
        S.w = fmaf(wt, S.w, b4.w);
    }
}

// ---------------------------------------------------------------------------
// Stage C (MFMA): per (b,h,chunk):
//   S[t][tau] = qs.ks (masked, diag = r.u.k);  Y = S@V + qs@Sc
//   qs = r*exp(Lexc), ks = k*exp(-Linc). All matmuls 16x16x32 bf16 MFMA.
// ---------------------------------------------------------------------------
__global__ __launch_bounds__(256) void chunk_out(const float* __restrict__ rb,
                                                 const float* __restrict__ kb,
                                                 const float* __restrict__ vb,
                                                 const float* __restrict__ lw,
                                                 const float* __restrict__ SbufT,
                                                 const float* __restrict__ tf,
                                                 float* __restrict__ y) {
    int bid = blockIdx.x;
    int c = bid & 15, h = (bid >> 4) & 15, b = bid >> 8;
    size_t gbase = ((size_t)(b * Tn + c * CL) * Hn + h) * 64;
    int tid = threadIdx.x;
    __shared__ alignas(16) __hip_bfloat16 qs[64][72];   // [t][ch]
    __shared__ alignas(16) __hip_bfloat16 ks[64][72];   // [tau][ch]
    __shared__ alignas(16) __hip_bfloat16 vsT[64][72];  // [v][tau]
    __shared__ alignas(16) __hip_bfloat16 scT[64][72];  // [v][ch]
    __shared__ alignas(16) float uni[64 * 68];          // linc, then asb
    __shared__ float wtp[4][64];
    __shared__ float diag[64];
    float (*linc)[68] = reinterpret_cast<float(*)[68]>(uni);
    __hip_bfloat16 (*asb)[72] = reinterpret_cast<__hip_bfloat16(*)[72]>(uni);
    int wave = tid >> 6, lane = tid & 63;
    // 1. decay prefix sums
    {
        float acc = 0.f;
        #pragma unroll
        for (int i = 0; i < 16; i++) {
            int t = wave * 16 + i;
            acc += lw[gbase + (size_t)t * 1024 + lane];
            linc[t][lane] = acc;
        }
        wtp[wave][lane] = acc;
    }
    __syncthreads();
    {
        float off = 0.f;
        for (int g = 0; g < wave; g++) off += wtp[g][lane];
        #pragma unroll
        for (int i = 0; i < 16; i++) linc[wave * 16 + i][lane] += off;
    }
    __syncthreads();
    // 2. build qs/ks/vsT/scT + diag
    int t4 = tid >> 2, c0 = (tid & 3) * 16;
    float dpart = 0.f;
    #pragma unroll
    for (int i = 0; i < 4; i++) {
        int ch = c0 + i * 4;
        size_t ga = gbase + (size_t)t4 * 1024 + ch;
        float4 r4 = *reinterpret_cast<const float4*>(rb + ga);
        float4 k4 = *reinterpret_cast<const float4*>(kb + ga);
        float4 v4 = *reinterpret_cast<const float4*>(vb + ga);
        float4 l4v = *reinterpret_cast<const float4*>(lw + ga);
        float4 u4 = *reinterpret_cast<const float4*>(tf + h * 64 + ch);
        float4 s4 = *reinterpret_cast<const float4*>(SbufT + (size_t)bid * 4096 + (size_t)t4 * 64 + ch);
        float rr[4] = {r4.x, r4.y, r4.z, r4.w};
        float kkv[4] = {k4.x, k4.y, k4.z, k4.w};
        float vv[4] = {v4.x, v4.y, v4.z, v4.w};
        float lwv[4] = {l4v.x, l4v.y, l4v.z, l4v.w};
        float uu[4] = {u4.x, u4.y, u4.z, u4.w};
        float ss[4] = {s4.x, s4.y, s4.z, s4.w};
        #pragma unroll
        for (int j = 0; j < 4; j++) {
            float li = linc[t4][ch + j];
            qs[t4][ch + j] = __float2bfloat16(rr[j] * expf(li - lwv[j]));
            ks[t4][ch + j] = __float2bfloat16(kkv[j] * expf(-li));
            vsT[ch + j][t4] = __float2bfloat16(vv[j]);
            scT[t4][ch + j] = __float2bfloat16(ss[j]);   // row t4 = v
            dpart = fmaf(rr[j] * uu[j], kkv[j], dpart);
        }
    }
    dpart += __shfl_xor(dpart, 1);
    dpart += __shfl_xor(dpart, 2);
    if ((tid & 3) == 0) diag[t4] = dpart;
    __syncthreads();        // linc dead; asb may now overwrite uni
    // 3. scores (wave owns t-strip): S = qs @ ks^T, masked store bf16
    int l15 = lane & 15, l4q = lane >> 4;
    #pragma unroll
    for (int nt = 0; nt < 4; nt++) {
        f32x4_t acc = {};
        if (nt <= wave) {
            #pragma unroll
            for (int kt = 0; kt < 2; kt++) {
                bf16x8_t a = *reinterpret_cast<const bf16x8_t*>(&qs[wave * 16 + l15][kt * 32 + l4q * 8]);
                bf16x8_t bb = *reinterpret_cast<const bf16x8_t*>(&ks[nt * 16 + l15][kt * 32 + l4q * 8]);
                acc = __builtin_amdgcn_mfma_f32_16x16x32_bf16(a, bb, acc, 0, 0, 0);
            }
        }
        #pragma unroll
        for (int q = 0; q < 4; q++) {
            int t = wave * 16 + l4q * 4 + q;
            int tau = nt * 16 + l15;
            float v = (tau < t) ? acc[q] : (tau == t ? diag[t] : 0.f);
            asb[t][tau] = __float2bfloat16(v);
        }
    }
    __syncthreads();
    // 4. Y = asb @ vsT^T (triangular trim) + qs @ scT^T
    #pragma unroll
    for (int nt = 0; nt < 4; nt++) {
        f32x4_t acc = {};
        int kmax = (wave >> 1) + 1;
        for (int kt = 0; kt < kmax; kt++) {
            bf16x8_t a = *reinterpret_cast<const bf16x8_t*>(&asb[wave * 16 + l15][kt * 32 + l4q * 8]);
            bf16x8_t bb = *reinterpret_cast<const bf16x8_t*>(&vsT[nt * 16 + l15][kt * 32 + l4q * 8]);
            acc = __builtin_amdgcn_mfma_f32_16x16x32_bf16(a, bb, acc, 0, 0, 0);
        }
        #pragma unroll
        for (int kt = 0; kt < 2; kt++) {
            bf16x8_t a = *reinterpret_cast<const bf16x8_t*>(&qs[wave * 16 + l15][kt * 32 + l4q * 8]);
            bf16x8_t bb = *reinterpret_cast<const bf16x8_t*>(&scT[nt * 16 + l15][kt * 32 + l4q * 8]);
            acc = __builtin_amdgcn_mfma_f32_16x16x32_bf16(a, bb, acc, 0, 0, 0);
        }
        #pragma unroll
        for (int q = 0; q < 4; q++) {
            int t = wave * 16 + l4q * 4 + q;
            y[gbase + (size_t)t * 1024 + nt * 16 + l15] = acc[q];
        }
    }
}

// ---------------------------------------------------------------------------
// GroupNorm per (bt,h) over 64 channels (after /8), *ln_w + ln_b, then *g.
// ---------------------------------------------------------------------------
__global__ __launch_bounds__(256) void gn_mul(const float* __restrict__ y,
                                              const __hip_bfloat16* __restrict__ g,
                                              const float* __restrict__ lnw,
                                              const float* __restrict__ lnb,
                                              __hip_bfloat16* __restrict__ fin) {
    int tid = threadIdx.x;
    int lane = tid & 63;
    int wv = tid >> 6;
    int grp = blockIdx.x * 4 + wv;    // bt*16 + h
    int h = grp & 15;
    size_t idx = (size_t)grp * 64 + lane;
    float val = y[idx] * 0.125f;
    float sum = val, sq = val * val;
    #pragma unroll
    for (int off = 32; off > 0; off >>= 1) {
        sum += __shfl_xor(sum, off, 64);
        sq  += __shfl_xor(sq,  off, 64);
    }
    float mu = sum * (1.f / 64.f);
    float var = sq * (1.f / 64.f) - mu * mu;
    float rs = rsqrtf(var + 1e-5f);
    float o = (val - mu) * rs * lnw[h * 64 + lane] + lnb[h * 64 + lane];
    fin[idx] = __float2bfloat16(o * __bfloat162float(g[idx]));
}

// ---------------------------------------------------------------------------
extern "C" void kernel_launch(void* const* d_in, const int* in_sizes, int n_in,
                              void* d_out, int out_size, void* d_ws, size_t ws_size,
                              hipStream_t stream) {
    (void)in_sizes; (void)n_in; (void)out_size; (void)ws_size;
    const float* x      = (const float*)d_in[0];
    const float* x_maa  = (const float*)d_in[1];
    const float* w_maa  = (const float*)d_in[2];
    const float* k_maa  = (const float*)d_in[3];
    const float* v_maa  = (const float*)d_in[4];
    const float* r_maa  = (const float*)d_in[5];
    const float* g_maa  = (const float*)d_in[6];
    const float* tm_w1  = (const float*)d_in[7];
    const float* tm_w2  = (const float*)d_in[8];
    const float* td_w1  = (const float*)d_in[9];
    const float* td_w2  = (const float*)d_in[10];
    const float* t_dec  = (const float*)d_in[11];
    const float* t_first= (const float*)d_in[12];
    const float* Wr     = (const float*)d_in[13];
    const float* Wk     = (const float*)d_in[14];
    const float* Wv     = (const float*)d_in[15];
    const float* Wg     = (const float*)d_in[16];
    const float* Wo     = (const float*)d_in[17];
    const float* ln_w   = (const float*)d_in[18];
    const float* ln_b   = (const float*)d_in[19];
    float* out = (float*)d_out;

    // Byte allocator, 256B aligned
    char* ws = (char*)d_ws;
    size_t off = 0;
    auto alloc = [&](size_t bytes) -> void* {
        void* p = ws + off;
        off = (off + bytes + 255) & ~(size_t)255;
        return p;
    };
    __hip_bfloat16* mixin = (__hip_bfloat16*)alloc(BTC * 4);  // bf16 used; slot also aliases rb (f32)
    float* mix160 = (float*)alloc((size_t)BT * 160 * 4);
    float* wxr    = (float*)alloc(BTC * 4);            // wx -> BcB -> ybuf
    __hip_bfloat16* kxb = (__hip_bfloat16*)alloc(BTC * 2);  // alias: fin
    __hip_bfloat16* vxb = (__hip_bfloat16*)alloc(BTC * 2);
    __hip_bfloat16* rxb = (__hip_bfloat16*)alloc(BTC * 2);  // rxb+gxb -> SbufT (16MB)
    __hip_bfloat16* gxb = (__hip_bfloat16*)alloc(BTC * 2);
    float* kb  = (float*)alloc(BTC * 4);
    float* vb  = (float*)alloc(BTC * 4);
    __hip_bfloat16* gb = (__hip_bfloat16*)alloc(BTC * 2);
    float* wl1 = (float*)alloc((size_t)BT * 64 * 4);   // alias: WtB
    float* lwb = (float*)alloc(BTC * 4);
    __hip_bfloat16* WrT = (__hip_bfloat16*)alloc((size_t)Cn * Cn * 2);
    __hip_bfloat16* WkT = (__hip_bfloat16*)alloc((size_t)Cn * Cn * 2);
    __hip_bfloat16* WvT = (__hip_bfloat16*)alloc((size_t)Cn * Cn * 2);
    __hip_bfloat16* WgT = (__hip_bfloat16*)alloc((size_t)Cn * Cn * 2);
    __hip_bfloat16* WoT = (__hip_bfloat16*)alloc((size_t)Cn * Cn * 2);
    __hip_bfloat16* tmw1T = (__hip_bfloat16*)alloc((size_t)160 * Cn * 2);
    // Aliases (stream-ordered; producers complete before reuse):
    float* rb    = (float*)mixin;  // r projection (mixin dead after LoRA1)
    float* BcB   = wxr;            // chunk contributions (wx dead after wl1 GEMM)
    float* ybuf  = wxr;            // recurrence out (BcB dead after chunk_scan)
    float* WtB   = wl1;            // chunk decay totals (wl1 dead after decay GEMM)
    float* SbufT = (float*)rxb;    // entry states (transposed), spans rxb+gxb
    __hip_bfloat16* fin = kxb;     // gn output (kxb dead after k projection)

    dim3 blk(256);
    // weight transpose+convert
    transp_bf16<<<dim3(32, 32), blk, 0, stream>>>(Wr, WrT, Cn, Cn);
    transp_bf16<<<dim3(32, 32), blk, 0, stream>>>(Wk, WkT, Cn, Cn);
    transp_bf16<<<dim3(32, 32), blk, 0, stream>>>(Wv, WvT, Cn, Cn);
    transp_bf16<<<dim3(32, 32), blk, 0, stream>>>(Wg, WgT, Cn, Cn);
    transp_bf16<<<dim3(32, 32), blk, 0, stream>>>(Wo, WoT, Cn, Cn);
    transp_bf16<<<dim3(5, 32),  blk, 0, stream>>>(tm_w1, tmw1T, Cn, 160);
    // token-mix LoRA (MFMA)
    prep_mixin<<<dim3((unsigned)((BTC + 255) / 256)), blk, 0, stream>>>(x, x_maa, mixin);
    gemm_mfma<1, false><<<dim3(2, 64), blk, 0, stream>>>(mixin, tmw1T, mix160, BT, 160, Cn);
    deltas_mix<<<dim3(4, 512), blk, 0, stream>>>(x, mix160, tm_w2,
                                                 w_maa, k_maa, v_maa, r_maa, g_maa,
                                                 wxr, kxb, vxb, rxb, gxb);
    // projections (bf16 MFMA)
    gemm_mfma<0, false><<<dim3(8, 64), blk, 0, stream>>>(rxb, WrT, rb, BT, Cn, Cn);
    gemm_mfma<0, false><<<dim3(8, 64), blk, 0, stream>>>(kxb, WkT, kb, BT, Cn, Cn);
    gemm_mfma<0, false><<<dim3(8, 64), blk, 0, stream>>>(vxb, WvT, vb, BT, Cn, Cn);
    gemm_mfma<2, true ><<<dim3(8, 64), blk, 0, stream>>>(gxb, WgT, gb, BT, Cn, Cn);
    // decay LoRA (f32, precision-sensitive)
    gemm_f32<1><<<dim3(1, 64), blk, 0, stream>>>(wxr, td_w1, wl1, BT, 64, Cn, nullptr);
    gemm_f32<3><<<dim3(16, 64), blk, 0, stream>>>(wl1, td_w2, lwb, BT, Cn, 64, t_dec);
    // chunked scan (MFMA)
    chunk_summary<<<dim3(Bn * Hn * NC), blk, 0, stream>>>(kb, vb, lwb, BcB, WtB);
    chunk_scan<<<dim3(Bn * Hn * 4), blk, 0, stream>>>(BcB, WtB, SbufT);
    chunk_out<<<dim3(Bn * Hn * NC), blk, 0, stream>>>(rb, kb, vb, lwb, SbufT, t_first, ybuf);
    // epilogue
    gn_mul<<<dim3(BT * Hn / 4), blk, 0, stream>>>(ybuf, gb, ln_w, ln_b, fin);
    gemm_mfma<0, false><<<dim3(8, 64), blk, 0, stream>>>(fin, WoT, out, BT, Cn, Cn);
}

// Round 6
// 268.430 us; speedup vs baseline: 6.6692x; 1.2050x over previous
//
#include <hip/hip_runtime.h>
#include <hip/hip_bf16.h>
#include <math.h>

// Problem constants
constexpr int Bn = 4, Tn = 1024, Cn = 1024, Hn = 16;
constexpr int BT = Bn * Tn;                 // 4096
constexpr long long BTC = (long long)BT * Cn;  // 4M elements
constexpr int CL = 64;                      // chunk length
constexpr int NC = Tn / CL;                 // 16 chunks

typedef __bf16 bf16x8_t __attribute__((ext_vector_type(8)));
typedef float f32x4_t __attribute__((ext_vector_type(4)));
typedef unsigned short us8_t __attribute__((ext_vector_type(8)));

// ---------------------------------------------------------------------------
// mix input for the token-mix LoRA: out = bf16(x + (x_prev - x)*x_maa[c])
// ---------------------------------------------------------------------------
__global__ __launch_bounds__(256) void prep_mixin(const float* __restrict__ x,
                                                  const float* __restrict__ x_maa,
                                                  __hip_bfloat16* __restrict__ out) {
    long long idx = (long long)blockIdx.x * 256 + threadIdx.x;
    if (idx >= BTC) return;
    int c  = (int)(idx & (Cn - 1));
    long long bt = idx >> 10;
    int t  = (int)(bt & (Tn - 1));
    float xv = x[idx];
    float xp = (t > 0) ? x[idx - Cn] : 0.f;
    out[idx] = __float2bfloat16(xv + (xp - xv) * x_maa[c]);
}

// ---------------------------------------------------------------------------
// Transpose + convert: W [R][Cc] f32 -> Wt [Cc][R] bf16  (R, Cc multiples of 32)
// ---------------------------------------------------------------------------
__global__ __launch_bounds__(256) void transp_bf16(const float* __restrict__ W,
                                                   __hip_bfloat16* __restrict__ Wt,
                                                   int R, int Cc) {
    __shared__ float tile[32][33];
    int c0 = blockIdx.x * 32, r0 = blockIdx.y * 32;
    int tx = threadIdx.x & 31, ty = threadIdx.x >> 5;
    #pragma unroll
    for (int i = 0; i < 4; i++)
        tile[ty + 8 * i][tx] = W[(size_t)(r0 + ty + 8 * i) * Cc + c0 + tx];
    __syncthreads();
    #pragma unroll
    for (int i = 0; i < 4; i++)
        Wt[(size_t)(c0 + ty + 8 * i) * R + r0 + tx] = __float2bfloat16(tile[tx][ty + 8 * i]);
}

// ---------------------------------------------------------------------------
// f32 tiled GEMM (decay LoRA GEMM2, precision-sensitive): C = A[M,K]@B[K,N].
// EPI: 3 logdecay (-exp(extra[col]+acc))
// ---------------------------------------------------------------------------
template <int EPI>
__global__ __launch_bounds__(256) void gemm_f32(const float* __restrict__ A,
                                                const float* __restrict__ Bm,
                                                float* __restrict__ C,
                                                int M, int N, int K,
                                                const float* __restrict__ extra) {
    __shared__ float As[16][64];
    __shared__ float Bs[16][64];
    int tid = threadIdx.x;
    int m0 = blockIdx.y * 64, n0 = blockIdx.x * 64;
    int tx = tid & 15, ty = tid >> 4;
    int ar = tid >> 2, ac = (tid & 3) * 4;
    int br = tid >> 4, bc = (tid & 15) * 4;
    float acc[4][4] = {};

    for (int k0 = 0; k0 < K; k0 += 16) {
        const float* ap = A + (size_t)(m0 + ar) * K + k0 + ac;
        float4 av = *reinterpret_cast<const float4*>(ap);
        As[ac + 0][ar] = av.x; As[ac + 1][ar] = av.y;
        As[ac + 2][ar] = av.z; As[ac + 3][ar] = av.w;
        float4 bv;
        if (n0 + bc + 3 < N) {
            bv = *reinterpret_cast<const float4*>(Bm + (size_t)(k0 + br) * N + n0 + bc);
        } else {
            float tmp[4];
            #pragma unroll
            for (int i = 0; i < 4; i++) {
                int col = n0 + bc + i;
                tmp[i] = (col < N) ? Bm[(size_t)(k0 + br) * N + col] : 0.f;
            }
            bv = make_float4(tmp[0], tmp[1], tmp[2], tmp[3]);
        }
        *reinterpret_cast<float4*>(&Bs[br][bc]) = bv;
        __syncthreads();
        #pragma unroll
        for (int kk = 0; kk < 16; kk++) {
            float4 a4 = *reinterpret_cast<const float4*>(&As[kk][ty * 4]);
            float4 b4 = *reinterpret_cast<const float4*>(&Bs[kk][tx * 4]);
            float aa[4] = {a4.x, a4.y, a4.z, a4.w};
            float bb[4] = {b4.x, b4.y, b4.z, b4.w};
            #pragma unroll
            for (int i = 0; i < 4; i++)
                #pragma unroll
                for (int j = 0; j < 4; j++)
                    acc[i][j] = fmaf(aa[i], bb[j], acc[i][j]);
        }
        __syncthreads();
    }

    #pragma unroll
    for (int i = 0; i < 4; i++) {
        int row = m0 + ty * 4 + i;
        #pragma unroll
        for (int j = 0; j < 4; j++) {
            int col = n0 + tx * 4 + j;
            if (col < N) {
                float v = acc[i][j];
                if (EPI == 3) v = -expf(extra[col] + v);
                C[(size_t)row * N + col] = v;
            }
        }
    }
}

// ---------------------------------------------------------------------------
// Split-K f32 GEMM for the decay LoRA1 ([4096,1024]@[1024,64], N==64).
// grid = (KS, M/64). Each block accumulates K-range K/KS into partials.
// ---------------------------------------------------------------------------
template <int KS>
__global__ __launch_bounds__(256) void gemm_f32_splitk(const float* __restrict__ A,
                                                       const float* __restrict__ Bm,
                                                       float* __restrict__ part,
                                                       int M, int N, int K) {
    __shared__ float As[16][64];
    __shared__ float Bs[16][64];
    int tid = threadIdx.x;
    int kp = blockIdx.x;
    int m0 = blockIdx.y * 64;
    int kbeg = kp * (K / KS), kend = kbeg + K / KS;
    int tx = tid & 15, ty = tid >> 4;
    int ar = tid >> 2, ac = (tid & 3) * 4;
    int br = tid >> 4, bc = (tid & 15) * 4;
    float acc[4][4] = {};

    for (int k0 = kbeg; k0 < kend; k0 += 16) {
        float4 av = *reinterpret_cast<const float4*>(A + (size_t)(m0 + ar) * K + k0 + ac);
        As[ac + 0][ar] = av.x; As[ac + 1][ar] = av.y;
        As[ac + 2][ar] = av.z; As[ac + 3][ar] = av.w;
        *reinterpret_cast<float4*>(&Bs[br][bc]) =
            *reinterpret_cast<const float4*>(Bm + (size_t)(k0 + br) * N + bc);
        __syncthreads();
        #pragma unroll
        for (int kk = 0; kk < 16; kk++) {
            float4 a4 = *reinterpret_cast<const float4*>(&As[kk][ty * 4]);
            float4 b4 = *reinterpret_cast<const float4*>(&Bs[kk][tx * 4]);
            float aa[4] = {a4.x, a4.y, a4.z, a4.w};
            float bb[4] = {b4.x, b4.y, b4.z, b4.w};
            #pragma unroll
            for (int i = 0; i < 4; i++)
                #pragma unroll
                for (int j = 0; j < 4; j++)
                    acc[i][j] = fmaf(aa[i], bb[j], acc[i][j]);
        }
        __syncthreads();
    }
    #pragma unroll
    for (int i = 0; i < 4; i++) {
        int row = m0 + ty * 4 + i;
        #pragma unroll
        for (int j = 0; j < 4; j++)
            part[((size_t)kp * M + row) * N + tx * 4 + j] = acc[i][j];
    }
}

// Reduce KS partials + tanh -> wl1
template <int KS>
__global__ __launch_bounds__(256) void splitk_reduce_tanh(const float* __restrict__ part,
                                                          float* __restrict__ outp,
                                                          int total, size_t stride) {
    int i = blockIdx.x * 256 + threadIdx.x;
    if (i >= total) return;
    float s = 0.f;
    #pragma unroll
    for (int kp = 0; kp < KS; kp++) s += part[kp * stride + i];
    outp[i] = tanhf(s);
}

// ---------------------------------------------------------------------------
// bf16 MFMA GEMM: C[M,N] = A[M,K] @ Bt[N,K]^T.  BM=64, BN=128, BK=64.
// 4 waves (2x2), wave tile 32x64, 16x16x32 MFMA, XOR-swizzled LDS.
// EPI: 0 none, 1 tanh, 2 silu.  OBF16: write bf16 output.
// ---------------------------------------------------------------------------
template <int EPI, bool OBF16>
__global__ __launch_bounds__(256) void gemm_mfma(const __hip_bfloat16* __restrict__ A,
                                                 const __hip_bfloat16* __restrict__ Bt,
                                                 void* __restrict__ Cout,
                                                 int M, int N, int K) {
    __shared__ alignas(16) unsigned short As[64 * 64];
    __shared__ alignas(16) unsigned short Bs[128 * 64];
    int tid = threadIdx.x;
    int m0 = blockIdx.y * 64, n0 = blockIdx.x * 128;
    int wave = tid >> 6, lane = tid & 63;
    int wm = (wave & 1) * 32, wn = (wave >> 1) * 64;
    int l15 = lane & 15, l4 = lane >> 4;
    f32x4_t acc[2][4] = {};

    for (int k0 = 0; k0 < K; k0 += 64) {
        #pragma unroll
        for (int p = 0; p < 2; p++) {
            int cch = tid + p * 256;            // 0..511
            int row = cch >> 3, slot = cch & 7;
            int s2 = slot ^ (row & 7);
            *reinterpret_cast<us8_t*>(&As[row * 64 + s2 * 8]) =
                *reinterpret_cast<const us8_t*>(&A[(size_t)(m0 + row) * K + k0 + slot * 8]);
        }
        #pragma unroll
        for (int p = 0; p < 4; p++) {
            int cch = tid + p * 256;            // 0..1023
            int row = cch >> 3, slot = cch & 7;
            int s2 = slot ^ (row & 7);
            int rowg = n0 + row; if (rowg > N - 1) rowg = N - 1;  // clamp
            *reinterpret_cast<us8_t*>(&Bs[row * 64 + s2 * 8]) =
                *reinterpret_cast<const us8_t*>(&Bt[(size_t)rowg * K + k0 + slot * 8]);
        }
        __syncthreads();
        #pragma unroll
        for (int kw = 0; kw < 2; kw++) {
            int slot = kw * 4 + l4;
            bf16x8_t af[2], bfr[4];
            #pragma unroll
            for (int f = 0; f < 2; f++) {
                int ar = wm + f * 16 + l15;
                af[f] = *reinterpret_cast<const bf16x8_t*>(&As[ar * 64 + (slot ^ (ar & 7)) * 8]);
            }
            #pragma unroll
            for (int f = 0; f < 4; f++) {
                int br = wn + f * 16 + l15;
                bfr[f] = *reinterpret_cast<const bf16x8_t*>(&Bs[br * 64 + (slot ^ (br & 7)) * 8]);
            }
            #pragma unroll
            for (int i = 0; i < 2; i++)
                #pragma unroll
                for (int j = 0; j < 4; j++)
                    acc[i][j] = __builtin_amdgcn_mfma_f32_16x16x32_bf16(af[i], bfr[j], acc[i][j], 0, 0, 0);
        }
        __syncthreads();
    }

    #pragma unroll
    for (int i = 0; i < 2; i++) {
        int rbase = m0 + wm + i * 16 + l4 * 4;
        #pragma unroll
        for (int j = 0; j < 4; j++) {
            int col = n0 + wn + j * 16 + l15;
            if (col < N) {
                #pragma unroll
                for (int q = 0; q < 4; q++) {
                    float v = acc[i][j][q];
                    if (EPI == 1) v = tanhf(v);
                    else if (EPI == 2) v = v / (1.f + expf(-v));
                    size_t o = (size_t)(rbase + q) * N + col;
                    if (OBF16) ((__hip_bfloat16*)Cout)[o] = __float2bfloat16(v);
                    else       ((float*)Cout)[o] = v;
                }
            }
        }
    }
}

// ---------------------------------------------------------------------------
// 5 mix deltas fused with wx/kx/vx/rx/gx build. Block = 8 bt-rows x 256 cols.
// ---------------------------------------------------------------------------
__global__ __launch_bounds__(256) void deltas_mix(const float* __restrict__ x,
                                                  const float* __restrict__ mix160,
                                                  const float* __restrict__ w2,
                                                  const float* __restrict__ wmaa,
                                                  const float* __restrict__ kmaa,
                                                  const float* __restrict__ vmaa,
                                                  const float* __restrict__ rmaa,
                                                  const float* __restrict__ gmaa,
                                                  float* __restrict__ wx,
                                                  __hip_bfloat16* __restrict__ kxb,
                                                  __hip_bfloat16* __restrict__ vxb,
                                                  __hip_bfloat16* __restrict__ rxb,
                                                  __hip_bfloat16* __restrict__ gxb) {
    int tid = threadIdx.x;
    int c = blockIdx.x * 256 + tid;
    int r0 = blockIdx.y * 8;
    __shared__ float m[8][160];
    for (int i = tid; i < 1280; i += 256)
        m[i / 160][i % 160] = mix160[(size_t)(r0 + i / 160) * 160 + (i % 160)];
    __syncthreads();
    float xv[8], sx[8];
    #pragma unroll
    for (int r = 0; r < 8; r++) {
        int row = r0 + r;
        int t = row & (Tn - 1);
        size_t idx = (size_t)row * Cn + c;
        float xvv = x[idx];
        float xp = (t > 0) ? x[idx - Cn] : 0.f;
        xv[r] = xvv;
        sx[r] = xp - xvv;
    }
    #pragma unroll
    for (int f = 0; f < 5; f++) {
        float acc[8];
        #pragma unroll
        for (int r = 0; r < 8; r++) acc[r] = 0.f;
        for (int dd = 0; dd < 32; dd++) {
            float wv = w2[(size_t)(f * 32 + dd) * Cn + c];
            #pragma unroll
            for (int r = 0; r < 8; r++)
                acc[r] = fmaf(m[r][f * 32 + dd], wv, acc[r]);
        }
        const float* maa = (f == 0) ? wmaa : (f == 1) ? kmaa : (f == 2) ? vmaa
                         : (f == 3) ? rmaa : gmaa;
        float mv = maa[c];
        #pragma unroll
        for (int r = 0; r < 8; r++) {
            size_t idx = (size_t)(r0 + r) * Cn + c;
            float val = xv[r] + sx[r] * (mv + acc[r]);
            if (f == 0)      wx[idx]  = val;
            else if (f == 1) kxb[idx] = __float2bfloat16(val);
            else if (f == 2) vxb[idx] = __float2bfloat16(val);
            else if (f == 3) rxb[idx] = __float2bfloat16(val);
            else             gxb[idx] = __float2bfloat16(val);
        }
    }
}

// ---------------------------------------------------------------------------
// Chunked WKV stage A (MFMA): per (b,h,chunk):
//   Wtot[ch] = exp(sum lw); Bc[k][v] = sum_tau kd[tau][k]*vs[tau][v]
// ---------------------------------------------------------------------------
__global__ __launch_bounds__(256) void chunk_summary(const float* __restrict__ kb,
                                                     const float* __restrict__ vb,
                                                     const float* __restrict__ lw,
                                                     float* __restrict__ Bc,
                                                     float* __restrict__ Wtot) {
    int bid = blockIdx.x;
    int c = bid & 15, h = (bid >> 4) & 15, b = bid >> 8;
    size_t gbase = ((size_t)(b * Tn + c * CL) * Hn + h) * 64;
    int tid = threadIdx.x;
    __shared__ float linc[64][68];
    __shared__ float wtp[4][64];
    __shared__ alignas(16) __hip_bfloat16 kdT[64][72];  // [ch][tau]
    __shared__ alignas(16) __hip_bfloat16 vsT[64][72];  // [v][tau]
    int wave = tid >> 6, lane = tid & 63;
    {
        float acc = 0.f;
        #pragma unroll
        for (int i = 0; i < 16; i++) {
            int t = wave * 16 + i;
            acc += lw[gbase + (size_t)t * 1024 + lane];
            linc[t][lane] = acc;
        }
        wtp[wave][lane] = acc;
    }
    __syncthreads();
    {
        float off = 0.f;
        for (int g = 0; g < wave; g++) off += wtp[g][lane];
        #pragma unroll
        for (int i = 0; i < 16; i++) linc[wave * 16 + i][lane] += off;
    }
    __syncthreads();
    int t4 = tid >> 2, c0 = (tid & 3) * 16;
    #pragma unroll
    for (int i = 0; i < 4; i++) {
        int ch = c0 + i * 4;
        size_t ga = gbase + (size_t)t4 * 1024 + ch;
        float4 k4 = *reinterpret_cast<const float4*>(kb + ga);
        float4 v4 = *reinterpret_cast<const float4*>(vb + ga);
        float kk[4] = {k4.x, k4.y, k4.z, k4.w};
        float vv[4] = {v4.x, v4.y, v4.z, v4.w};
        #pragma unroll
        for (int j = 0; j < 4; j++) {
            float li = linc[t4][ch + j];
            float lend = linc[63][ch + j];
            kdT[ch + j][t4] = __float2bfloat16(kk[j] * expf(lend - li));
            vsT[ch + j][t4] = __float2bfloat16(vv[j]);
        }
    }
    if (tid < 64) Wtot[(size_t)bid * 64 + tid] = expf(linc[63][tid]);
    __syncthreads();
    int l15 = lane & 15, l4q = lane >> 4;
    #pragma unroll
    for (int nt = 0; nt < 4; nt++) {
        f32x4_t acc = {};
        #pragma unroll
        for (int kt = 0; kt < 2; kt++) {
            bf16x8_t a = *reinterpret_cast<const bf16x8_t*>(&kdT[wave * 16 + l15][kt * 32 + l4q * 8]);
            bf16x8_t bb = *reinterpret_cast<const bf16x8_t*>(&vsT[nt * 16 + l15][kt * 32 + l4q * 8]);
            acc = __builtin_amdgcn_mfma_f32_16x16x32_bf16(a, bb, acc, 0, 0, 0);
        }
        #pragma unroll
        for (int q = 0; q < 4; q++) {
            int krow = wave * 16 + l4q * 4 + q;
            Bc[(size_t)bid * 4096 + (size_t)krow * 64 + nt * 16 + l15] = acc[q];
        }
    }
}

// ---------------------------------------------------------------------------
// Stage B: sequential scan over NC=16 chunk states; writes TRANSPOSED entry
// states SbufT[v][k].
// ---------------------------------------------------------------------------
__global__ __launch_bounds__(256) void chunk_scan(const float* __restrict__ Bc,
                                                  const float* __restrict__ Wtot,
                                                  float* __restrict__ SbufT) {
    int bid = blockIdx.x;
    int bh = bid >> 2, vg = bid & 3;
    int kk = threadIdx.x >> 2;
    int v = vg * 16 + (threadIdx.x & 3) * 4;
    float4 S = make_float4(0.f, 0.f, 0.f, 0.f);
    for (int c = 0; c < NC; c++) {
        size_t base = (size_t)(bh * NC + c) * 4096;
        SbufT[base + (size_t)(v + 0) * 64 + kk] = S.x;
        SbufT[base + (size_t)(v + 1) * 64 + kk] = S.y;
        SbufT[base + (size_t)(v + 2) * 64 + kk] = S.z;
        SbufT[base + (size_t)(v + 3) * 64 + kk] = S.w;
        float wt = Wtot[(size_t)(bh * NC + c) * 64 + kk];
        float4 b4 = *reinterpret_cast<const float4*>(Bc + base + (size_t)kk * 64 + v);
        S.x = fmaf(wt, S.x, b4.x);
        S.y = fmaf(wt, S.y, b4.y);
        S.z = fmaf(wt, S.z, b4.z);
        S.w = fmaf(wt, S.w, b4.w);
    }
}

// ---------------------------------------------------------------------------
// Stage C (MFMA): Y = mask(qs@ks^T, diag) @ V + qs @ Sc
// ---------------------------------------------------------------------------
__global__ __launch_bounds__(256) void chunk_out(const float* __restrict__ rb,
                                                 const float* __restrict__ kb,
                                                 const float* __restrict__ vb,
                                                 const float* __restrict__ lw,
                                                 const float* __restrict__ SbufT,
                                                 const float* __restrict__ tf,
                                                 float* __restrict__ y) {
    int bid = blockIdx.x;
    int c = bid & 15, h = (bid >> 4) & 15, b = bid >> 8;
    size_t gbase = ((size_t)(b * Tn + c * CL) * Hn + h) * 64;
    int tid = threadIdx.x;
    __shared__ alignas(16) __hip_bfloat16 qs[64][72];   // [t][ch]
    __shared__ alignas(16) __hip_bfloat16 ks[64][72];   // [tau][ch]
    __shared__ alignas(16) __hip_bfloat16 vsT[64][72];  // [v][tau]
    __shared__ alignas(16) __hip_bfloat16 scT[64][72];  // [v][ch]
    __shared__ alignas(16) float uni[64 * 68];          // linc, then asb
    __shared__ float wtp[4][64];
    __shared__ float diag[64];
    float (*linc)[68] = reinterpret_cast<float(*)[68]>(uni);
    __hip_bfloat16 (*asb)[72] = reinterpret_cast<__hip_bfloat16(*)[72]>(uni);
    int wave = tid >> 6, lane = tid & 63;
    {
        float acc = 0.f;
        #pragma unroll
        for (int i = 0; i < 16; i++) {
            int t = wave * 16 + i;
            acc += lw[gbase + (size_t)t * 1024 + lane];
            linc[t][lane] = acc;
        }
        wtp[wave][lane] = acc;
    }
    __syncthreads();
    {
        float off = 0.f;
        for (int g = 0; g < wave; g++) off += wtp[g][lane];
        #pragma unroll
        for (int i = 0; i < 16; i++) linc[wave * 16 + i][lane] += off;
    }
    __syncthreads();
    int t4 = tid >> 2, c0 = (tid & 3) * 16;
    float dpart = 0.f;
    #pragma unroll
    for (int i = 0; i < 4; i++) {
        int ch = c0 + i * 4;
        size_t ga = gbase + (size_t)t4 * 1024 + ch;
        float4 r4 = *reinterpret_cast<const float4*>(rb + ga);
        float4 k4 = *reinterpret_cast<const float4*>(kb + ga);
        float4 v4 = *reinterpret_cast<const float4*>(vb + ga);
        float4 l4v = *reinterpret_cast<const float4*>(lw + ga);
        float4 u4 = *reinterpret_cast<const float4*>(tf + h * 64 + ch);
        float4 s4 = *reinterpret_cast<const float4*>(SbufT + (size_t)bid * 4096 + (size_t)t4 * 64 + ch);
        float rr[4] = {r4.x, r4.y, r4.z, r4.w};
        float kkv[4] = {k4.x, k4.y, k4.z, k4.w};
        float vv[4] = {v4.x, v4.y, v4.z, v4.w};
        float lwv[4] = {l4v.x, l4v.y, l4v.z, l4v.w};
        float uu[4] = {u4.x, u4.y, u4.z, u4.w};
        float ss[4] = {s4.x, s4.y, s4.z, s4.w};
        #pragma unroll
        for (int j = 0; j < 4; j++) {
            float li = linc[t4][ch + j];
            qs[t4][ch + j] = __float2bfloat16(rr[j] * expf(li - lwv[j]));
            ks[t4][ch + j] = __float2bfloat16(kkv[j] * expf(-li));
            vsT[ch + j][t4] = __float2bfloat16(vv[j]);
            scT[t4][ch + j] = __float2bfloat16(ss[j]);   // row t4 = v
            dpart = fmaf(rr[j] * uu[j], kkv[j], dpart);
        }
    }
    dpart += __shfl_xor(dpart, 1);
    dpart += __shfl_xor(dpart, 2);
    if ((tid & 3) == 0) diag[t4] = dpart;
    __syncthreads();        // linc dead; asb may now overwrite uni
    int l15 = lane & 15, l4q = lane >> 4;
    #pragma unroll
    for (int nt = 0; nt < 4; nt++) {
        f32x4_t acc = {};
        if (nt <= wave) {
            #pragma unroll
            for (int kt = 0; kt < 2; kt++) {
                bf16x8_t a = *reinterpret_cast<const bf16x8_t*>(&qs[wave * 16 + l15][kt * 32 + l4q * 8]);
                bf16x8_t bb = *reinterpret_cast<const bf16x8_t*>(&ks[nt * 16 + l15][kt * 32 + l4q * 8]);
                acc = __builtin_amdgcn_mfma_f32_16x16x32_bf16(a, bb, acc, 0, 0, 0);
            }
        }
        #pragma unroll
        for (int q = 0; q < 4; q++) {
            int t = wave * 16 + l4q * 4 + q;
            int tau = nt * 16 + l15;
            float v = (tau < t) ? acc[q] : (tau == t ? diag[t] : 0.f);
            asb[t][tau] = __float2bfloat16(v);
        }
    }
    __syncthreads();
    #pragma unroll
    for (int nt = 0; nt < 4; nt++) {
        f32x4_t acc = {};
        int kmax = (wave >> 1) + 1;
        for (int kt = 0; kt < kmax; kt++) {
            bf16x8_t a = *reinterpret_cast<const bf16x8_t*>(&asb[wave * 16 + l15][kt * 32 + l4q * 8]);
            bf16x8_t bb = *reinterpret_cast<const bf16x8_t*>(&vsT[nt * 16 + l15][kt * 32 + l4q * 8]);
            acc = __builtin_amdgcn_mfma_f32_16x16x32_bf16(a, bb, acc, 0, 0, 0);
        }
        #pragma unroll
        for (int kt = 0; kt < 2; kt++) {
            bf16x8_t a = *reinterpret_cast<const bf16x8_t*>(&qs[wave * 16 + l15][kt * 32 + l4q * 8]);
            bf16x8_t bb = *reinterpret_cast<const bf16x8_t*>(&scT[nt * 16 + l15][kt * 32 + l4q * 8]);
            acc = __builtin_amdgcn_mfma_f32_16x16x32_bf16(a, bb, acc, 0, 0, 0);
        }
        #pragma unroll
        for (int q = 0; q < 4; q++) {
            int t = wave * 16 + l4q * 4 + q;
            y[gbase + (size_t)t * 1024 + nt * 16 + l15] = acc[q];
        }
    }
}

// ---------------------------------------------------------------------------
// GroupNorm per (bt,h) over 64 channels (after /8), *ln_w + ln_b, then *g.
// ---------------------------------------------------------------------------
__global__ __launch_bounds__(256) void gn_mul(const float* __restrict__ y,
                                              const __hip_bfloat16* __restrict__ g,
                                              const float* __restrict__ lnw,
                                              const float* __restrict__ lnb,
                                              __hip_bfloat16* __restrict__ fin) {
    int tid = threadIdx.x;
    int lane = tid & 63;
    int wv = tid >> 6;
    int grp = blockIdx.x * 4 + wv;    // bt*16 + h
    int h = grp & 15;
    size_t idx = (size_t)grp * 64 + lane;
    float val = y[idx] * 0.125f;
    float sum = val, sq = val * val;
    #pragma unroll
    for (int off = 32; off > 0; off >>= 1) {
        sum += __shfl_xor(sum, off, 64);
        sq  += __shfl_xor(sq,  off, 64);
    }
    float mu = sum * (1.f / 64.f);
    float var = sq * (1.f / 64.f) - mu * mu;
    float rs = rsqrtf(var + 1e-5f);
    float o = (val - mu) * rs * lnw[h * 64 + lane] + lnb[h * 64 + lane];
    fin[idx] = __float2bfloat16(o * __bfloat162float(g[idx]));
}

// ---------------------------------------------------------------------------
extern "C" void kernel_launch(void* const* d_in, const int* in_sizes, int n_in,
                              void* d_out, int out_size, void* d_ws, size_t ws_size,
                              hipStream_t stream) {
    (void)in_sizes; (void)n_in; (void)out_size; (void)ws_size;
    const float* x      = (const float*)d_in[0];
    const float* x_maa  = (const float*)d_in[1];
    const float* w_maa  = (const float*)d_in[2];
    const float* k_maa  = (const float*)d_in[3];
    const float* v_maa  = (const float*)d_in[4];
    const float* r_maa  = (const float*)d_in[5];
    const float* g_maa  = (const float*)d_in[6];
    const float* tm_w1  = (const float*)d_in[7];
    const float* tm_w2  = (const float*)d_in[8];
    const float* td_w1  = (const float*)d_in[9];
    const float* td_w2  = (const float*)d_in[10];
    const float* t_dec  = (const float*)d_in[11];
    const float* t_first= (const float*)d_in[12];
    const float* Wr     = (const float*)d_in[13];
    const float* Wk     = (const float*)d_in[14];
    const float* Wv     = (const float*)d_in[15];
    const float* Wg     = (const float*)d_in[16];
    const float* Wo     = (const float*)d_in[17];
    const float* ln_w   = (const float*)d_in[18];
    const float* ln_b   = (const float*)d_in[19];
    float* out = (float*)d_out;

    // Byte allocator, 256B aligned
    char* ws = (char*)d_ws;
    size_t off = 0;
    auto alloc = [&](size_t bytes) -> void* {
        void* p = ws + off;
        off = (off + bytes + 255) & ~(size_t)255;
        return p;
    };
    __hip_bfloat16* mixin = (__hip_bfloat16*)alloc(BTC * 4);  // bf16 used; slot also aliases rb (f32)
    float* mix160 = (float*)alloc((size_t)BT * 160 * 4);
    float* wxr    = (float*)alloc(BTC * 4);            // wx -> BcB -> ybuf
    __hip_bfloat16* kxb = (__hip_bfloat16*)alloc(BTC * 2);  // alias: fin
    __hip_bfloat16* vxb = (__hip_bfloat16*)alloc(BTC * 2);
    __hip_bfloat16* rxb = (__hip_bfloat16*)alloc(BTC * 2);  // rxb+gxb -> SbufT (16MB)
    __hip_bfloat16* gxb = (__hip_bfloat16*)alloc(BTC * 2);
    float* kb  = (float*)alloc(BTC * 4);
    float* vb  = (float*)alloc(BTC * 4);
    __hip_bfloat16* gb = (__hip_bfloat16*)alloc(BTC * 2);
    float* wl1 = (float*)alloc((size_t)BT * 64 * 4);   // alias: WtB
    float* lwb = (float*)alloc(BTC * 4);
    __hip_bfloat16* WrT = (__hip_bfloat16*)alloc((size_t)Cn * Cn * 2);
    __hip_bfloat16* WkT = (__hip_bfloat16*)alloc((size_t)Cn * Cn * 2);
    __hip_bfloat16* WvT = (__hip_bfloat16*)alloc((size_t)Cn * Cn * 2);
    __hip_bfloat16* WgT = (__hip_bfloat16*)alloc((size_t)Cn * Cn * 2);
    __hip_bfloat16* WoT = (__hip_bfloat16*)alloc((size_t)Cn * Cn * 2);
    __hip_bfloat16* tmw1T = (__hip_bfloat16*)alloc((size_t)160 * Cn * 2);
    float* skpart = (float*)alloc((size_t)8 * BT * 64 * 4);   // split-K partials (8MB)
    // Aliases (stream-ordered; producers complete before reuse):
    float* rb    = (float*)mixin;  // r projection (mixin dead after LoRA1)
    float* BcB   = wxr;            // chunk contributions (wx dead after splitk)
    float* ybuf  = wxr;            // recurrence out (BcB dead after chunk_scan)
    float* WtB   = wl1;            // chunk decay totals (wl1 dead after decay GEMM)
    float* SbufT = (float*)rxb;    // entry states (transposed), spans rxb+gxb
    __hip_bfloat16* fin = kxb;     // gn output (kxb dead after k projection)

    dim3 blk(256);
    // weight transpose+convert
    transp_bf16<<<dim3(32, 32), blk, 0, stream>>>(Wr, WrT, Cn, Cn);
    transp_bf16<<<dim3(32, 32), blk, 0, stream>>>(Wk, WkT, Cn, Cn);
    transp_bf16<<<dim3(32, 32), blk, 0, stream>>>(Wv, WvT, Cn, Cn);
    transp_bf16<<<dim3(32, 32), blk, 0, stream>>>(Wg, WgT, Cn, Cn);
    transp_bf16<<<dim3(32, 32), blk, 0, stream>>>(Wo, WoT, Cn, Cn);
    transp_bf16<<<dim3(5, 32),  blk, 0, stream>>>(tm_w1, tmw1T, Cn, 160);
    // token-mix LoRA (MFMA)
    prep_mixin<<<dim3((unsigned)((BTC + 255) / 256)), blk, 0, stream>>>(x, x_maa, mixin);
    gemm_mfma<1, false><<<dim3(2, 64), blk, 0, stream>>>(mixin, tmw1T, mix160, BT, 160, Cn);
    deltas_mix<<<dim3(4, 512), blk, 0, stream>>>(x, mix160, tm_w2,
                                                 w_maa, k_maa, v_maa, r_maa, g_maa,
                                                 wxr, kxb, vxb, rxb, gxb);
    // projections (bf16 MFMA)
    gemm_mfma<0, false><<<dim3(8, 64), blk, 0, stream>>>(rxb, WrT, rb, BT, Cn, Cn);
    gemm_mfma<0, false><<<dim3(8, 64), blk, 0, stream>>>(kxb, WkT, kb, BT, Cn, Cn);
    gemm_mfma<0, false><<<dim3(8, 64), blk, 0, stream>>>(vxb, WvT, vb, BT, Cn, Cn);
    gemm_mfma<2, true ><<<dim3(8, 64), blk, 0, stream>>>(gxb, WgT, gb, BT, Cn, Cn);
    // decay LoRA1 (f32 split-K, 512 blocks) + fused reduce/tanh
    gemm_f32_splitk<8><<<dim3(8, 64), blk, 0, stream>>>(wxr, td_w1, skpart, BT, 64, Cn);
    splitk_reduce_tanh<8><<<dim3(BT * 64 / 256), blk, 0, stream>>>(skpart, wl1, BT * 64,
                                                                   (size_t)BT * 64);
    // decay GEMM2 (f32, precision-sensitive)
    gemm_f32<3><<<dim3(16, 64), blk, 0, stream>>>(wl1, td_w2, lwb, BT, Cn, 64, t_dec);
    // chunked scan (MFMA)
    chunk_summary<<<dim3(Bn * Hn * NC), blk, 0, stream>>>(kb, vb, lwb, BcB, WtB);
    chunk_scan<<<dim3(Bn * Hn * 4), blk, 0, stream>>>(BcB, WtB, SbufT);
    chunk_out<<<dim3(Bn * Hn * NC), blk, 0, stream>>>(rb, kb, vb, lwb, SbufT, t_first, ybuf);
    // epilogue
    gn_mul<<<dim3(BT * Hn / 4), blk, 0, stream>>>(ybuf, gb, ln_w, ln_b, fin);
    gemm_mfma<0, false><<<dim3(8, 64), blk, 0, stream>>>(fin, WoT, out, BT, Cn, Cn);
}